// Round 14
// baseline (275.538 us; speedup 1.0000x reference)
//
#include <hip/hip_runtime.h>
#include <math.h>

#define NN 50000
#define EE 800000
#define SBLK ((NN + 255) / 256)   // 196 scan blocks
#define NBE ((EE + 255) / 256)    // 3125 edge blocks

typedef short bf16x8 __attribute__((ext_vector_type(8)));
typedef float f32x4 __attribute__((ext_vector_type(4)));
typedef unsigned u32x4 __attribute__((ext_vector_type(4)));
typedef unsigned short ushort_t;
#define MFMA16(a, b, c) __builtin_amdgcn_mfma_f32_16x16x32_bf16(a, b, c, 0, 0, 0)

__device__ __forceinline__ float sigmoidf_(float x) { return 1.0f / (1.0f + __expf(-x)); }

__device__ __forceinline__ unsigned short f2bf(float f) {
    unsigned u = __builtin_bit_cast(unsigned, f);
    u += 0x7FFFu + ((u >> 16) & 1u);
    return (unsigned short)(u >> 16);
}
__device__ __forceinline__ float bf2f(unsigned short v) {
    unsigned u = (unsigned)v << 16;
    return __builtin_bit_cast(float, u);
}
__device__ __forceinline__ unsigned pk2(float a, float b) {
    return ((unsigned)f2bf(b) << 16) | (unsigned)f2bf(a);
}

// packed bf16 weight table sizes (bf16 elements)
#define W1ST_A 104   // INK=96 + 8
#define W1ST_B 72    // INK=64 + 8
#define C1ST_  72
#define PW1A (64 * W1ST_A)
#define PW2A (32 * C1ST_)
#define PW1B (64 * W1ST_B)
#define PW2B (32 * C1ST_)

// ---------------- node history LSTM + bf16 padded xu table ----------------
__global__ __launch_bounds__(256) void node_lstm_k(
    const float* __restrict__ x, const float* __restrict__ u,
    const float* __restrict__ h0, const float* __restrict__ c0,
    const float* __restrict__ Wih, const float* __restrict__ Whh,
    const float* __restrict__ bih, const float* __restrict__ bhh,
    ushort_t* __restrict__ xu16, float* __restrict__ h_out, float* __restrict__ c_out)
{
    __shared__ float sWih[80 * 37];
    __shared__ float sWhh[80 * 20];
    __shared__ float sb[80];
    for (int i = threadIdx.x; i < 80 * 37; i += 256) sWih[i] = Wih[i];
    for (int i = threadIdx.x; i < 80 * 20; i += 256) sWhh[i] = Whh[i];
    if (threadIdx.x < 80) sb[threadIdx.x] = bih[threadIdx.x] + bhh[threadIdx.x];
    __syncthreads();
    int n = blockIdx.x * 256 + threadIdx.x;
    if (n >= NN) return;

    float xu[40];
#pragma unroll
    for (int k = 0; k < 5; k++) xu[k] = x[n * 5 + k];
#pragma unroll
    for (int k = 0; k < 32; k++) xu[5 + k] = u[n * 32 + k];
    xu[37] = 0.f; xu[38] = 0.f; xu[39] = 0.f;

    {
        unsigned w[20];
#pragma unroll
        for (int k = 0; k < 20; k++) w[k] = pk2(xu[2 * k], xu[2 * k + 1]);
        uint4* dst = (uint4*)(xu16 + (size_t)n * 40);
#pragma unroll
        for (int q = 0; q < 5; q++)
            dst[q] = make_uint4(w[q * 4], w[q * 4 + 1], w[q * 4 + 2], w[q * 4 + 3]);
    }

    float h[20];
#pragma unroll
    for (int k = 0; k < 20; k++) h[k] = h0[n * 20 + k];

#pragma unroll 1
    for (int r = 0; r < 20; r++) {
        float gi = sb[r], gf = sb[20 + r], gg = sb[40 + r], go = sb[60 + r];
#pragma unroll
        for (int k = 0; k < 37; k++) {
            float v = xu[k];
            gi = fmaf(v, sWih[r * 37 + k], gi);
            gf = fmaf(v, sWih[(20 + r) * 37 + k], gf);
            gg = fmaf(v, sWih[(40 + r) * 37 + k], gg);
            go = fmaf(v, sWih[(60 + r) * 37 + k], go);
        }
#pragma unroll
        for (int k = 0; k < 20; k++) {
            float v = h[k];
            gi = fmaf(v, sWhh[r * 20 + k], gi);
            gf = fmaf(v, sWhh[(20 + r) * 20 + k], gf);
            gg = fmaf(v, sWhh[(40 + r) * 20 + k], gg);
            go = fmaf(v, sWhh[(60 + r) * 20 + k], go);
        }
        float cr = c0[n * 20 + r];
        float cn = sigmoidf_(gf) * cr + sigmoidf_(gi) * tanhf(gg);
        float hn = sigmoidf_(go) * tanhf(cn);
        h_out[n * 20 + r] = hn;
        c_out[n * 20 + r] = cn;
    }
}

// ---------------- CSR build ----------------
__global__ __launch_bounds__(256) void csr_count_k(const int* __restrict__ col,
                                                   int* __restrict__ count)
{
    int e = blockIdx.x * 256 + threadIdx.x;
    if (e < EE) atomicAdd(&count[col[e]], 1);
}

// ---------------- scan1 + weight pre-pack fused ----------------
__global__ __launch_bounds__(256) void scan1p_k(
    const int* __restrict__ count, int* __restrict__ bsum,
    const float* __restrict__ We1, const float* __restrict__ We2,
    const float* __restrict__ Wo1, const float* __restrict__ Wo2,
    ushort_t* __restrict__ pw)
{
    __shared__ int red[256];
    int t = threadIdx.x;
    if (blockIdx.x == SBLK) {
        ushort_t* pw1a = pw;
        ushort_t* pw2a = pw1a + PW1A;
        ushort_t* pw1b = pw2a + PW2A;
        ushort_t* pw2b = pw1b + PW1B;
        for (int i = t; i < PW1A; i += 256) {
            int n = i / W1ST_A, nk = i - n * W1ST_A;
            int kp = 0; bool z = false;
            if (nk < 37) kp = nk;
            else if (nk < 40) z = true;
            else if (nk < 77) kp = nk - 3;
            else if (nk < 80) z = true;
            else if (nk < 84) kp = nk - 6;
            else z = true;
            pw1a[i] = z ? (ushort_t)0 : f2bf(We1[kp * 64 + n]);
        }
        for (int i = t; i < PW2A; i += 256) {
            int n = i / C1ST_, k = i - n * C1ST_;
            pw2a[i] = (k < 64) ? f2bf(We2[k * 32 + n]) : (ushort_t)0;
        }
        for (int i = t; i < PW1B; i += 256) {
            int n = i / W1ST_B, nk = i - n * W1ST_B;
            int kp = 0; bool z = false;
            if (nk < 28) kp = nk;
            else if (nk < 32) z = true;
            else if (nk < 64) kp = nk - 4;
            else z = true;
            pw1b[i] = z ? (ushort_t)0 : f2bf(Wo1[kp * 64 + n]);
        }
        for (int i = t; i < PW2B; i += 256) {
            int n = i / C1ST_, k = i - n * C1ST_;
            pw2b[i] = (k < 64) ? f2bf(Wo2[k * 32 + n]) : (ushort_t)0;
        }
        return;
    }
    int i = blockIdx.x * 256 + t;
    red[t] = (i < NN) ? count[i] : 0;
    __syncthreads();
#pragma unroll
    for (int d = 128; d > 0; d >>= 1) {
        if (t < d) red[t] += red[t + d];
        __syncthreads();
    }
    if (t == 0) bsum[blockIdx.x] = red[0];
}

__global__ __launch_bounds__(256) void scan2_k(const int* __restrict__ bsum,
                                               int* __restrict__ bpre)
{
    __shared__ int s[256];
    int t = threadIdx.x;
    int v = (t < SBLK) ? bsum[t] : 0;
    s[t] = v;
    __syncthreads();
#pragma unroll
    for (int d = 1; d < 256; d <<= 1) {
        int w = (t >= d) ? s[t - d] : 0;
        __syncthreads();
        s[t] += w;
        __syncthreads();
    }
    if (t < SBLK) bpre[t] = s[t] - v;
}

__global__ __launch_bounds__(256) void scan3_k(const int* __restrict__ count,
                                               const int* __restrict__ bpre,
                                               int* __restrict__ offset,
                                               float* __restrict__ cntf)
{
    __shared__ int s[256];
    int t = threadIdx.x;
    int i = blockIdx.x * 256 + t;
    int v = (i < NN) ? count[i] : 0;
    s[t] = v;
    __syncthreads();
#pragma unroll
    for (int d = 1; d < 256; d <<= 1) {
        int w = (t >= d) ? s[t - d] : 0;
        __syncthreads();
        s[t] += w;
        __syncthreads();
    }
    if (i < NN) {
        offset[i] = bpre[blockIdx.x] + s[t] - v;
        cntf[i] = (float)v;
    }
}

// fill CSR: one packed uint4 {row, col, ea01, ea23} per slot (non-temporal store)
__global__ __launch_bounds__(256) void csr_fill4_k(const int* __restrict__ row,
                                                   const int* __restrict__ col,
                                                   const float* __restrict__ eattr,
                                                   const int* __restrict__ offset,
                                                   int* __restrict__ cursor,
                                                   uint4* __restrict__ edat)
{
    int e = blockIdx.x * 256 + threadIdx.x;
    if (e >= EE) return;
    int c = col[e];
    int pos = atomicAdd(&cursor[c], 1);
    int slot = offset[c] + pos;
    float4 ev = *(const float4*)&eattr[(size_t)e * 4];
    u32x4 v = {(unsigned)row[e], (unsigned)c, pk2(ev.x, ev.y), pk2(ev.z, ev.w)};
    __builtin_nontemporal_store(v, (u32x4*)&edat[slot]);
}

// ---------------- gather helper: one quarter's B-fragments ----------------
template <int F, int STRIDE, int S1>
__device__ __forceinline__ void gather_frag(
    const ushort_t* __restrict__ feat, const uint4* __restrict__ edat,
    size_t slotBase, int q, int lr, int jb, bf16x8* xf)
{
    size_t slot = slotBase + (size_t)q * 16 + lr;
    uint4 ed = edat[slot];
    const ushort_t* xr = feat + (size_t)ed.x * STRIDE;
    const ushort_t* xc = feat + (size_t)ed.y * STRIDE;
    xf[0] = *(const bf16x8*)(xr + jb * 8);
    if (F == 37) {
        const ushort_t* p1 = (jb == 0) ? (xr + 32) : (xc + (jb - 1) * 8);
        xf[1] = *(const bf16x8*)p1;
        bf16x8 v;
        if (jb < 2) {
            v = *(const bf16x8*)((jb == 0) ? (xc + 24) : (xc + 32));
        } else if (jb == 2) {
            uint4 t = make_uint4(ed.z, ed.w, 0u, 0u);
            v = __builtin_bit_cast(bf16x8, t);
        } else {
            uint4 t = make_uint4(0u, 0u, 0u, 0u);
            v = __builtin_bit_cast(bf16x8, t);
        }
        xf[2] = v;
    } else {
        if (jb < 3) {
            xf[1] = *(const bf16x8*)(xc + jb * 8);
        } else {
            uint2 lo = *(const uint2*)(xc + 24);
            uint4 t = make_uint4(lo.x, lo.y, ed.z, ed.w);
            xf[1] = __builtin_bit_cast(bf16x8, t);
        }
    }
}

// ---------------- fused 2-layer edge MLP + in-block segment sum ----------------
// edat uint4 coalesced; 16 edges/pass, 2-deep gather pipeline; bf16 msg tile;
// bijective XCD-aware block swizzle for gather L2 locality.
template <int F, int STRIDE, int INK>
__global__ __launch_bounds__(256, 4) void edge_mlp_fused_k(
    const ushort_t* __restrict__ feat,
    const uint4* __restrict__ edat,
    const int* __restrict__ offset, const int* __restrict__ count,
    const ushort_t* __restrict__ pw,
    const float* __restrict__ b1, const float* __restrict__ b2,
    float* __restrict__ agg)
{
    constexpr int S1 = INK / 32;
    constexpr int W1ST = INK + 8;
    constexpr int C1ST = C1ST_;
    constexpr int MST = 260;                         // bf16 msg tile stride
    constexpr int ABYTES = (64 * W1ST + 32 * C1ST + 4 * 16 * C1ST) * 2;
    constexpr int BBYTES = 32 * MST * 2;             // msg tile [32 feat][260] bf16
    constexpr int UBYTES = (ABYTES > BBYTES) ? ABYTES : BBYTES;
    constexpr int NU4 = (64 * W1ST + 32 * C1ST) / 8;

    __shared__ __align__(16) char ldsu[UBYTES];
    __shared__ int colLds[256];
    __shared__ unsigned char segStartA[256];
    __shared__ short segEndA[256];                   // negative => complete segment
    __shared__ int segCnt;

    ushort_t* sW1 = (ushort_t*)ldsu;                 // [64][W1ST]
    ushort_t* sW2 = sW1 + 64 * W1ST;                 // [32][C1ST]
    ushort_t* sC1 = sW2 + 32 * C1ST;                 // [4][16][C1ST]
    ushort_t* msgT16 = (ushort_t*)ldsu;              // [32][MST] bf16

    // bijective XCD swizzle: each XCD gets a contiguous chunk of blocks
    int nwg = gridDim.x;
    int qq = nwg >> 3, rr = nwg & 7;
    int xcd = blockIdx.x & 7, idx = blockIdx.x >> 3;
    int wgid = (xcd < rr ? xcd * (qq + 1) : rr * (qq + 1) + (xcd - rr) * qq) + idx;

    const int tid = threadIdx.x;
    const int B0 = wgid * 256;
    if (tid == 0) segCnt = 0;
    colLds[tid] = (int)edat[B0 + tid].y;

    // stage pre-packed weights: straight uint4 copy
    {
        const uint4* src = (const uint4*)pw;
        uint4* dst = (uint4*)ldsu;
        for (int i = tid; i < NU4; i += 256) dst[i] = src[i];
    }
    __syncthreads();

    // build segment list (col is sorted within the block)
    {
        bool isStart = (tid == 0) || (colLds[tid] != colLds[tid - 1]);
        if (isStart) {
            int node = colLds[tid];
            int off = offset[node], cn = count[node];
            int e = off + cn - B0; if (e > 256) e = 256;
            bool fullseg = (off >= B0) && (off + cn <= B0 + 256);
            int j = atomicAdd(&segCnt, 1);
            segStartA[j] = (unsigned char)tid;
            segEndA[j] = (short)(fullseg ? -e : e);
        }
    }

    const int wave = tid >> 6, lane = tid & 63;
    const int lr = lane & 15, jb = lane >> 4;
    const size_t slotBase = (size_t)B0 + (size_t)wave * 64;
    const float4* b1v = (const float4*)b1;
    ushort_t* myC1 = sC1 + wave * 16 * C1ST;         // [16][C1ST]
    const float bb2_0 = b2[lr], bb2_1 = b2[16 + lr];

    // compute one 16-edge quarter: layer1 -> C1 -> layer2 into (o0,o1)
    auto compute = [&](const bf16x8* xf, f32x4& o0, f32x4& o1) {
        f32x4 acc1[4];
#pragma unroll
        for (int mh = 0; mh < 4; mh++) {
            float4 bv = b1v[mh * 4 + jb];
            acc1[mh] = f32x4{bv.x, bv.y, bv.z, bv.w};
        }
#pragma unroll
        for (int s = 0; s < S1; s++) {
#pragma unroll
            for (int mh = 0; mh < 4; mh++) {
                bf16x8 wf = *(const bf16x8*)&sW1[(mh * 16 + lr) * W1ST + s * 32 + jb * 8];
                acc1[mh] = MFMA16(wf, xf[s], acc1[mh]);
            }
        }
#pragma unroll
        for (int mh = 0; mh < 4; mh++) {
            f32x4 a = acc1[mh];
            unsigned w0 = pk2(fmaxf(a[0], 0.f), fmaxf(a[1], 0.f));
            unsigned w1 = pk2(fmaxf(a[2], 0.f), fmaxf(a[3], 0.f));
            *(uint2*)&myC1[lr * C1ST + mh * 16 + jb * 4] = make_uint2(w0, w1);
        }
        o0 = f32x4{bb2_0, bb2_0, bb2_0, bb2_0};
        o1 = f32x4{bb2_1, bb2_1, bb2_1, bb2_1};
#pragma unroll
        for (int s2 = 0; s2 < 2; s2++) {
            bf16x8 w2f0 = *(const bf16x8*)&sW2[lr * C1ST + s2 * 32 + jb * 8];
            bf16x8 w2f1 = *(const bf16x8*)&sW2[(16 + lr) * C1ST + s2 * 32 + jb * 8];
            bf16x8 a2 = *(const bf16x8*)&myC1[lr * C1ST + s2 * 32 + jb * 8];
            o0 = MFMA16(a2, w2f0, o0);
            o1 = MFMA16(a2, w2f1, o1);
        }
    };

    f32x4 a00, a01, a10, a11, a20, a21, a30, a31;
    bf16x8 xfA[S1], xfB[S1];
    gather_frag<F, STRIDE, S1>(feat, edat, slotBase, 0, lr, jb, xfA);
    gather_frag<F, STRIDE, S1>(feat, edat, slotBase, 1, lr, jb, xfB);
    compute(xfA, a00, a01);
    gather_frag<F, STRIDE, S1>(feat, edat, slotBase, 2, lr, jb, xfA);
    compute(xfB, a10, a11);
    gather_frag<F, STRIDE, S1>(feat, edat, slotBase, 3, lr, jb, xfB);
    compute(xfA, a20, a21);
    compute(xfB, a30, a31);

    // all waves done with sW1/sW2/sC1 -> alias the region as the bf16 msg tile
    __syncthreads();
#define DUMPQ(qq_, A0, A1) { \
        int row = wave * 64 + (qq_) * 16 + jb * 4; \
        { f32x4 a = (A0); ushort_t* dst = &msgT16[(size_t)lr * MST + row]; \
          *(uint2*)dst = make_uint2(pk2(a[0], a[1]), pk2(a[2], a[3])); } \
        { f32x4 a = (A1); ushort_t* dst = &msgT16[(size_t)(16 + lr) * MST + row]; \
          *(uint2*)dst = make_uint2(pk2(a[0], a[1]), pk2(a[2], a[3])); } }
    DUMPQ(0, a00, a01)
    DUMPQ(1, a10, a11)
    DUMPQ(2, a20, a21)
    DUMPQ(3, a30, a31)
#undef DUMPQ
    __syncthreads();

    // per-node reduction: wave w handles segments w, w+4, ...
    {
        int f = lane & 31;
        int h = lane >> 5;
        const ushort_t* mrow = msgT16 + (size_t)f * MST;
        int nseg = segCnt;
        for (int j = wave; j < nseg; j += 4) {
            int s = segStartA[j];
            int ev = segEndA[j];
            bool fullseg = ev < 0;
            int e = fullseg ? -ev : ev;
            int node = colLds[s];
            float sum = 0.f;
            for (int i = s + h; i < e; i += 2) sum += bf2f(mrow[i]);
            sum += __shfl_xor(sum, 32);
            if (lane < 32) {
                float* dst = &agg[(size_t)node * 32 + f];
                if (fullseg) *dst = sum;
                else atomicAdd(dst, sum);
            }
        }
    }
}

// ---------------- edge history LSTM + bf16 padded full table ----------------
__global__ __launch_bounds__(256) void edge_lstm_k(
    const float* __restrict__ agg, const float* __restrict__ cnt,
    const float* __restrict__ h0, const float* __restrict__ c0,
    const float* __restrict__ Wih, const float* __restrict__ Whh,
    const float* __restrict__ bih, const float* __restrict__ bhh,
    const float* __restrict__ node_h,
    float* __restrict__ h_out, float* __restrict__ c_out, ushort_t* __restrict__ full16)
{
    __shared__ float sWih[32 * 32];
    __shared__ float sWhh[32 * 8];
    __shared__ float sb[32];
    for (int i = threadIdx.x; i < 32 * 32; i += 256) sWih[i] = Wih[i];
    for (int i = threadIdx.x; i < 32 * 8; i += 256) sWhh[i] = Whh[i];
    if (threadIdx.x < 32) sb[threadIdx.x] = bih[threadIdx.x] + bhh[threadIdx.x];
    __syncthreads();
    int n = blockIdx.x * 256 + threadIdx.x;
    if (n >= NN) return;

    float inv = 1.0f / fmaxf(cnt[n], 1.0f);
    float msg[32];
#pragma unroll
    for (int k = 0; k < 32; k++) msg[k] = agg[(size_t)n * 32 + k] * inv;
    float h[8];
#pragma unroll
    for (int k = 0; k < 8; k++) h[k] = h0[n * 8 + k];

    float fl[32];
#pragma unroll
    for (int k = 0; k < 20; k++) fl[k] = node_h[n * 20 + k];
    fl[28] = 0.f; fl[29] = 0.f; fl[30] = 0.f; fl[31] = 0.f;

#pragma unroll
    for (int r = 0; r < 8; r++) {
        float gi = sb[r], gf = sb[8 + r], gg = sb[16 + r], go = sb[24 + r];
#pragma unroll
        for (int k = 0; k < 32; k++) {
            float v = msg[k];
            gi = fmaf(v, sWih[r * 32 + k], gi);
            gf = fmaf(v, sWih[(8 + r) * 32 + k], gf);
            gg = fmaf(v, sWih[(16 + r) * 32 + k], gg);
            go = fmaf(v, sWih[(24 + r) * 32 + k], go);
        }
#pragma unroll
        for (int k = 0; k < 8; k++) {
            float v = h[k];
            gi = fmaf(v, sWhh[r * 8 + k], gi);
            gf = fmaf(v, sWhh[(8 + r) * 8 + k], gf);
            gg = fmaf(v, sWhh[(16 + r) * 8 + k], gg);
            go = fmaf(v, sWhh[(24 + r) * 8 + k], go);
        }
        float cr = c0[n * 8 + r];
        float cn = sigmoidf_(gf) * cr + sigmoidf_(gi) * tanhf(gg);
        float hn = sigmoidf_(go) * tanhf(cn);
        h_out[n * 8 + r] = hn;
        c_out[n * 8 + r] = cn;
        fl[20 + r] = hn;
    }
    unsigned w[16];
#pragma unroll
    for (int k = 0; k < 16; k++) w[k] = pk2(fl[2 * k], fl[2 * k + 1]);
    uint4* dst = (uint4*)(full16 + (size_t)n * 32);
#pragma unroll
    for (int q = 0; q < 4; q++)
        dst[q] = make_uint4(w[q * 4], w[q * 4 + 1], w[q * 4 + 2], w[q * 4 + 3]);
}

// ---------------- output node MLP (reads bf16 full) ----------------
__global__ __launch_bounds__(256) void node_out_k(
    const ushort_t* __restrict__ full16, const float* __restrict__ agg2, const float* __restrict__ cnt,
    const float* __restrict__ W1, const float* __restrict__ b1,
    const float* __restrict__ W2, const float* __restrict__ b2,
    float* __restrict__ out)
{
    __shared__ __align__(16) float sW1[60 * 64];
    __shared__ __align__(16) float sW2[64 * 4];
    __shared__ float sb1[64];
    __shared__ float sb2[4];
    for (int i = threadIdx.x; i < 60 * 64; i += 256) sW1[i] = W1[i];
    for (int i = threadIdx.x; i < 64 * 4; i += 256) sW2[i] = W2[i];
    if (threadIdx.x < 64) sb1[threadIdx.x] = b1[threadIdx.x];
    if (threadIdx.x < 4) sb2[threadIdx.x] = b2[threadIdx.x];
    __syncthreads();
    int n = blockIdx.x * 256 + threadIdx.x;
    if (n >= NN) return;

    float in[60];
    const ushort_t* fr = full16 + (size_t)n * 32;
#pragma unroll
    for (int k = 0; k < 28; k++) in[k] = bf2f(fr[k]);
    float inv = 1.0f / fmaxf(cnt[n], 1.0f);
#pragma unroll
    for (int k = 0; k < 32; k++) in[28 + k] = agg2[(size_t)n * 32 + k] * inv;

    float o[4] = {sb2[0], sb2[1], sb2[2], sb2[3]};
#pragma unroll 1
    for (int j = 0; j < 64; j += 4) {
        float s[4] = {sb1[j], sb1[j + 1], sb1[j + 2], sb1[j + 3]};
#pragma unroll
        for (int k = 0; k < 60; k++) {
            float4 w = *(const float4*)&sW1[k * 64 + j];
            s[0] = fmaf(in[k], w.x, s[0]);
            s[1] = fmaf(in[k], w.y, s[1]);
            s[2] = fmaf(in[k], w.z, s[2]);
            s[3] = fmaf(in[k], w.w, s[3]);
        }
#pragma unroll
        for (int jj = 0; jj < 4; jj++) {
            float sv = fmaxf(s[jj], 0.0f);
            float4 w = *(const float4*)&sW2[(j + jj) * 4];
            o[0] = fmaf(sv, w.x, o[0]);
            o[1] = fmaf(sv, w.y, o[1]);
            o[2] = fmaf(sv, w.z, o[2]);
            o[3] = fmaf(sv, w.w, o[3]);
        }
    }
#pragma unroll
    for (int m = 0; m < 4; m++) out[n * 4 + m] = o[m];
}

// ---------------- fallback atomic edge MLP (reads bf16 tables) ----------------
template <int F, int STRIDE, bool DO_CNT>
__global__ __launch_bounds__(256) void edge_mlp_atomic_k(
    const ushort_t* __restrict__ feat,
    const int* __restrict__ row, const int* __restrict__ col,
    const float* __restrict__ eattr,
    const float* __restrict__ W1, const float* __restrict__ b1,
    const float* __restrict__ W2, const float* __restrict__ b2,
    float* __restrict__ agg, float* __restrict__ cnt)
{
    constexpr int IN = 2 * F + 4;
    __shared__ __align__(16) float sW1[IN * 64];
    __shared__ __align__(16) float sW2[64 * 32];
    __shared__ float sb1[64];
    __shared__ float sb2[32];
    for (int i = threadIdx.x; i < IN * 64; i += 256) sW1[i] = W1[i];
    for (int i = threadIdx.x; i < 64 * 32; i += 256) sW2[i] = W2[i];
    if (threadIdx.x < 64) sb1[threadIdx.x] = b1[threadIdx.x];
    if (threadIdx.x < 32) sb2[threadIdx.x] = b2[threadIdx.x];
    __syncthreads();
    int e = blockIdx.x * 256 + threadIdx.x;
    if (e >= EE) return;

    int r = row[e], c = col[e];
    float h[IN];
#pragma unroll
    for (int k = 0; k < F; k++) h[k] = bf2f(feat[(size_t)r * STRIDE + k]);
#pragma unroll
    for (int k = 0; k < F; k++) h[F + k] = bf2f(feat[(size_t)c * STRIDE + k]);
    float4 ev = *(const float4*)&eattr[(size_t)e * 4];
    h[2 * F] = ev.x; h[2 * F + 1] = ev.y; h[2 * F + 2] = ev.z; h[2 * F + 3] = ev.w;

    float out[32];
#pragma unroll
    for (int m = 0; m < 32; m++) out[m] = sb2[m];
#pragma unroll 1
    for (int j = 0; j < 64; j += 4) {
        float s[4] = {sb1[j], sb1[j + 1], sb1[j + 2], sb1[j + 3]};
#pragma unroll
        for (int k = 0; k < IN; k++) {
            float4 w = *(const float4*)&sW1[k * 64 + j];
            s[0] = fmaf(h[k], w.x, s[0]);
            s[1] = fmaf(h[k], w.y, s[1]);
            s[2] = fmaf(h[k], w.z, s[2]);
            s[3] = fmaf(h[k], w.w, s[3]);
        }
        s[0] = fmaxf(s[0], 0.f); s[1] = fmaxf(s[1], 0.f);
        s[2] = fmaxf(s[2], 0.f); s[3] = fmaxf(s[3], 0.f);
#pragma unroll
        for (int jj = 0; jj < 4; jj++) {
#pragma unroll
            for (int m = 0; m < 32; m += 4) {
                float4 w = *(const float4*)&sW2[(j + jj) * 32 + m];
                out[m]     = fmaf(s[jj], w.x, out[m]);
                out[m + 1] = fmaf(s[jj], w.y, out[m + 1]);
                out[m + 2] = fmaf(s[jj], w.z, out[m + 2]);
                out[m + 3] = fmaf(s[jj], w.w, out[m + 3]);
            }
        }
    }
    float* dst = &agg[(size_t)c * 32];
#pragma unroll
    for (int m = 0; m < 32; m++) atomicAdd(&dst[m], out[m]);
    if (DO_CNT) atomicAdd(&cnt[c], 1.0f);
}

extern "C" void kernel_launch(void* const* d_in, const int* in_sizes, int n_in,
                              void* d_out, int out_size, void* d_ws, size_t ws_size,
                              hipStream_t stream) {
    (void)in_sizes; (void)n_in; (void)out_size;
    const float* x      = (const float*)d_in[0];
    const float* u      = (const float*)d_in[1];
    const int*   ei     = (const int*)d_in[2];
    const float* eattr  = (const float*)d_in[3];
    const float* hn_h   = (const float*)d_in[4];
    const float* hn_c   = (const float*)d_in[5];
    const float* he_h   = (const float*)d_in[6];
    const float* he_c   = (const float*)d_in[7];
    const float* Wih_n  = (const float*)d_in[8];
    const float* Whh_n  = (const float*)d_in[9];
    const float* bih_n  = (const float*)d_in[10];
    const float* bhh_n  = (const float*)d_in[11];
    const float* Wih_e  = (const float*)d_in[12];
    const float* Whh_e  = (const float*)d_in[13];
    const float* bih_e  = (const float*)d_in[14];
    const float* bhh_e  = (const float*)d_in[15];
    const float* We1    = (const float*)d_in[16];
    const float* be1    = (const float*)d_in[17];
    const float* We2    = (const float*)d_in[18];
    const float* be2    = (const float*)d_in[19];
    const float* Wo1    = (const float*)d_in[20];
    const float* bo1    = (const float*)d_in[21];
    const float* Wo2    = (const float*)d_in[22];
    const float* bo2    = (const float*)d_in[23];
    const float* Wn1    = (const float*)d_in[24];
    const float* bn1    = (const float*)d_in[25];
    const float* Wn2    = (const float*)d_in[26];
    const float* bn2    = (const float*)d_in[27];

    const int* row = ei;
    const int* col = ei + EE;

    float* out = (float*)d_out;
    float* out_y   = out;                        // [N,4]
    float* node_h  = out + (size_t)NN * 4;       // [N,20]
    float* node_c  = out + (size_t)NN * 24;      // [N,20]
    float* edge_h  = out + (size_t)NN * 44;      // [N,8]
    float* edge_c  = out + (size_t)NN * 52;      // [N,8]

    int nb_n = (NN + 255) / 256;
    int nb_e = NBE;

    // ---- workspace layout ----
    ushort_t* xu16   = (ushort_t*)d_ws;
    ushort_t* full16 = xu16 + (size_t)NN * 40;
    float* agg  = (float*)(full16 + (size_t)NN * 32);
    float* cntf = agg + (size_t)NN * 32;
    float* agg2 = cntf + NN;
    int* count  = (int*)(agg2 + (size_t)NN * 32);
    int* cursor = count + NN;
    int* offset = cursor + NN;
    int* bsum   = offset + NN;
    int* bpre   = bsum + SBLK;
    size_t pw_off = ((size_t)((char*)(bpre + SBLK) - (char*)d_ws) + 15) & ~(size_t)15;
    ushort_t* pw = (ushort_t*)((char*)d_ws + pw_off);
    size_t edat_off = ((pw_off + (size_t)(PW1A + PW2A + PW1B + PW2B) * 2) + 15) & ~(size_t)15;
    uint4* edat = (uint4*)((char*)d_ws + edat_off);
    size_t needed = edat_off + (size_t)EE * 16;

    if (ws_size >= needed) {
        // zero agg | cntf | agg2 | count | cursor in one contiguous memset
        hipError_t _e = hipMemsetAsync(agg, 0, (size_t)NN * (32 + 1 + 32 + 1 + 1) * sizeof(float), stream);
        (void)_e;

        node_lstm_k<<<nb_n, 256, 0, stream>>>(x, u, hn_h, hn_c, Wih_n, Whh_n, bih_n, bhh_n,
                                              xu16, node_h, node_c);
        csr_count_k<<<nb_e, 256, 0, stream>>>(col, count);
        scan1p_k<<<SBLK + 1, 256, 0, stream>>>(count, bsum, We1, We2, Wo1, Wo2, pw);
        scan2_k<<<1, 256, 0, stream>>>(bsum, bpre);
        scan3_k<<<SBLK, 256, 0, stream>>>(count, bpre, offset, cntf);
        csr_fill4_k<<<nb_e, 256, 0, stream>>>(row, col, eattr, offset, cursor, edat);

        edge_mlp_fused_k<37, 40, 96><<<EE / 256, 256, 0, stream>>>(
            xu16, edat, offset, count, pw, be1, be2, agg);
        edge_lstm_k<<<nb_n, 256, 0, stream>>>(agg, cntf, he_h, he_c, Wih_e, Whh_e, bih_e, bhh_e,
                                              node_h, edge_h, edge_c, full16);
        edge_mlp_fused_k<28, 32, 64><<<EE / 256, 256, 0, stream>>>(
            full16, edat, offset, count, pw + PW1A + PW2A, bo1, bo2, agg2);
        node_out_k<<<nb_n, 256, 0, stream>>>(full16, agg2, cntf, Wn1, bn1, Wn2, bn2, out_y);
    } else {
        // fallback: atomic scatter path
        hipError_t _e = hipMemsetAsync(agg, 0, (size_t)NN * (32 + 1 + 32) * sizeof(float), stream);
        (void)_e;
        node_lstm_k<<<nb_n, 256, 0, stream>>>(x, u, hn_h, hn_c, Wih_n, Whh_n, bih_n, bhh_n,
                                              xu16, node_h, node_c);
        edge_mlp_atomic_k<37, 40, true><<<nb_e, 256, 0, stream>>>(xu16, row, col, eattr,
                                                                  We1, be1, We2, be2, agg, cntf);
        edge_lstm_k<<<nb_n, 256, 0, stream>>>(agg, cntf, he_h, he_c, Wih_e, Whh_e, bih_e, bhh_e,
                                              node_h, edge_h, edge_c, full16);
        edge_mlp_atomic_k<28, 32, false><<<nb_e, 256, 0, stream>>>(full16, row, col, eattr,
                                                                   Wo1, bo1, Wo2, bo2, agg2, nullptr);
        node_out_k<<<nb_n, 256, 0, stream>>>(full16, agg2, cntf, Wn1, bn1, Wn2, bn2, out_y);
    }
}

// Round 15
// 256.686 us; speedup vs baseline: 1.0734x; 1.0734x over previous
//
#include <hip/hip_runtime.h>
#include <math.h>

#define NN 50000
#define EE 800000
#define SBLK ((NN + 255) / 256)   // 196 scan blocks

typedef short bf16x8 __attribute__((ext_vector_type(8)));
typedef float f32x4 __attribute__((ext_vector_type(4)));
typedef unsigned short ushort_t;
#define MFMA16(a, b, c) __builtin_amdgcn_mfma_f32_16x16x32_bf16(a, b, c, 0, 0, 0)

__device__ __forceinline__ float sigmoidf_(float x) { return 1.0f / (1.0f + __expf(-x)); }

__device__ __forceinline__ unsigned short f2bf(float f) {
    unsigned u = __builtin_bit_cast(unsigned, f);
    u += 0x7FFFu + ((u >> 16) & 1u);
    return (unsigned short)(u >> 16);
}
__device__ __forceinline__ float bf2f(unsigned short v) {
    unsigned u = (unsigned)v << 16;
    return __builtin_bit_cast(float, u);
}
__device__ __forceinline__ unsigned pk2(float a, float b) {
    return ((unsigned)f2bf(b) << 16) | (unsigned)f2bf(a);
}

// packed bf16 weight table sizes (bf16 elements)
#define W1ST_A 104   // INK=96 + 8
#define W1ST_B 72    // INK=64 + 8
#define C1ST_  72
#define PW1A (64 * W1ST_A)
#define PW2A (32 * C1ST_)
#define PW1B (64 * W1ST_B)
#define PW2B (32 * C1ST_)

// ---------------- pre-pack both edge-MLP weight sets to bf16 LDS layout ----------------
__global__ __launch_bounds__(256) void pack_w_k(
    const float* __restrict__ We1, const float* __restrict__ We2,
    const float* __restrict__ Wo1, const float* __restrict__ Wo2,
    ushort_t* __restrict__ pw)
{
    ushort_t* pw1a = pw;
    ushort_t* pw2a = pw1a + PW1A;
    ushort_t* pw1b = pw2a + PW2A;
    ushort_t* pw2b = pw1b + PW1B;
    int tid = threadIdx.x;

    for (int i = tid; i < PW1A; i += 256) {
        int n = i / W1ST_A, nk = i - n * W1ST_A;
        int kp = 0; bool z = false;
        if (nk < 37) kp = nk;
        else if (nk < 40) z = true;
        else if (nk < 77) kp = nk - 3;
        else if (nk < 80) z = true;
        else if (nk < 84) kp = nk - 6;
        else z = true;
        pw1a[i] = z ? (ushort_t)0 : f2bf(We1[kp * 64 + n]);
    }
    for (int i = tid; i < PW2A; i += 256) {
        int n = i / C1ST_, k = i - n * C1ST_;
        pw2a[i] = (k < 64) ? f2bf(We2[k * 32 + n]) : (ushort_t)0;
    }
    for (int i = tid; i < PW1B; i += 256) {
        int n = i / W1ST_B, nk = i - n * W1ST_B;
        int kp = 0; bool z = false;
        if (nk < 28) kp = nk;
        else if (nk < 32) z = true;
        else if (nk < 64) kp = nk - 4;
        else z = true;
        pw1b[i] = z ? (ushort_t)0 : f2bf(Wo1[kp * 64 + n]);
    }
    for (int i = tid; i < PW2B; i += 256) {
        int n = i / C1ST_, k = i - n * C1ST_;
        pw2b[i] = (k < 64) ? f2bf(Wo2[k * 32 + n]) : (ushort_t)0;
    }
}

// ---------------- node history LSTM + bf16 padded xu table ----------------
__global__ __launch_bounds__(256) void node_lstm_k(
    const float* __restrict__ x, const float* __restrict__ u,
    const float* __restrict__ h0, const float* __restrict__ c0,
    const float* __restrict__ Wih, const float* __restrict__ Whh,
    const float* __restrict__ bih, const float* __restrict__ bhh,
    ushort_t* __restrict__ xu16, float* __restrict__ h_out, float* __restrict__ c_out)
{
    __shared__ float sWih[80 * 37];
    __shared__ float sWhh[80 * 20];
    __shared__ float sb[80];
    for (int i = threadIdx.x; i < 80 * 37; i += 256) sWih[i] = Wih[i];
    for (int i = threadIdx.x; i < 80 * 20; i += 256) sWhh[i] = Whh[i];
    if (threadIdx.x < 80) sb[threadIdx.x] = bih[threadIdx.x] + bhh[threadIdx.x];
    __syncthreads();
    int n = blockIdx.x * 256 + threadIdx.x;
    if (n >= NN) return;

    float xu[40];
#pragma unroll
    for (int k = 0; k < 5; k++) xu[k] = x[n * 5 + k];
#pragma unroll
    for (int k = 0; k < 32; k++) xu[5 + k] = u[n * 32 + k];
    xu[37] = 0.f; xu[38] = 0.f; xu[39] = 0.f;

    {
        unsigned w[20];
#pragma unroll
        for (int k = 0; k < 20; k++) w[k] = pk2(xu[2 * k], xu[2 * k + 1]);
        uint4* dst = (uint4*)(xu16 + (size_t)n * 40);
#pragma unroll
        for (int q = 0; q < 5; q++)
            dst[q] = make_uint4(w[q * 4], w[q * 4 + 1], w[q * 4 + 2], w[q * 4 + 3]);
    }

    float h[20];
#pragma unroll
    for (int k = 0; k < 20; k++) h[k] = h0[n * 20 + k];

#pragma unroll 1
    for (int r = 0; r < 20; r++) {
        float gi = sb[r], gf = sb[20 + r], gg = sb[40 + r], go = sb[60 + r];
#pragma unroll
        for (int k = 0; k < 37; k++) {
            float v = xu[k];
            gi = fmaf(v, sWih[r * 37 + k], gi);
            gf = fmaf(v, sWih[(20 + r) * 37 + k], gf);
            gg = fmaf(v, sWih[(40 + r) * 37 + k], gg);
            go = fmaf(v, sWih[(60 + r) * 37 + k], go);
        }
#pragma unroll
        for (int k = 0; k < 20; k++) {
            float v = h[k];
            gi = fmaf(v, sWhh[r * 20 + k], gi);
            gf = fmaf(v, sWhh[(20 + r) * 20 + k], gf);
            gg = fmaf(v, sWhh[(40 + r) * 20 + k], gg);
            go = fmaf(v, sWhh[(60 + r) * 20 + k], go);
        }
        float cr = c0[n * 20 + r];
        float cn = sigmoidf_(gf) * cr + sigmoidf_(gi) * tanhf(gg);
        float hn = sigmoidf_(go) * tanhf(cn);
        h_out[n * 20 + r] = hn;
        c_out[n * 20 + r] = cn;
    }
}

// ---------------- CSR build ----------------
__global__ __launch_bounds__(256) void csr_count_k(const int* __restrict__ col,
                                                   int* __restrict__ count)
{
    int e = blockIdx.x * 256 + threadIdx.x;
    if (e < EE) atomicAdd(&count[col[e]], 1);
}

__global__ __launch_bounds__(256) void scan1_k(const int* __restrict__ count,
                                               int* __restrict__ bsum)
{
    __shared__ int red[256];
    int t = threadIdx.x;
    int i = blockIdx.x * 256 + t;
    red[t] = (i < NN) ? count[i] : 0;
    __syncthreads();
#pragma unroll
    for (int d = 128; d > 0; d >>= 1) {
        if (t < d) red[t] += red[t + d];
        __syncthreads();
    }
    if (t == 0) bsum[blockIdx.x] = red[0];
}

__global__ __launch_bounds__(256) void scan2_k(const int* __restrict__ bsum,
                                               int* __restrict__ bpre)
{
    __shared__ int s[256];
    int t = threadIdx.x;
    int v = (t < SBLK) ? bsum[t] : 0;
    s[t] = v;
    __syncthreads();
#pragma unroll
    for (int d = 1; d < 256; d <<= 1) {
        int w = (t >= d) ? s[t - d] : 0;
        __syncthreads();
        s[t] += w;
        __syncthreads();
    }
    if (t < SBLK) bpre[t] = s[t] - v;
}

__global__ __launch_bounds__(256) void scan3_k(const int* __restrict__ count,
                                               const int* __restrict__ bpre,
                                               int* __restrict__ offset,
                                               float* __restrict__ cntf)
{
    __shared__ int s[256];
    int t = threadIdx.x;
    int i = blockIdx.x * 256 + t;
    int v = (i < NN) ? count[i] : 0;
    s[t] = v;
    __syncthreads();
#pragma unroll
    for (int d = 1; d < 256; d <<= 1) {
        int w = (t >= d) ? s[t - d] : 0;
        __syncthreads();
        s[t] += w;
        __syncthreads();
    }
    if (i < NN) {
        offset[i] = bpre[blockIdx.x] + s[t] - v;
        cntf[i] = (float)v;
    }
}

// fill CSR: one packed uint4 {row, col, ea01, ea23} per slot
__global__ __launch_bounds__(256) void csr_fill4_k(const int* __restrict__ row,
                                                   const int* __restrict__ col,
                                                   const float* __restrict__ eattr,
                                                   const int* __restrict__ offset,
                                                   int* __restrict__ cursor,
                                                   uint4* __restrict__ edat)
{
    int e = blockIdx.x * 256 + threadIdx.x;
    if (e >= EE) return;
    int c = col[e];
    int pos = atomicAdd(&cursor[c], 1);
    int slot = offset[c] + pos;
    float4 ev = *(const float4*)&eattr[(size_t)e * 4];
    edat[slot] = make_uint4((unsigned)row[e], (unsigned)c, pk2(ev.x, ev.y), pk2(ev.z, ev.w));
}

// ---------------- fused 2-layer edge MLP + in-block segment sum ----------------
// Round-7 structure (edat uint4 coalesced) + quarter-C1 (16 edges/pass) and
// bf16 msg tile -> LDS ~29KB -> 5 blocks/CU.
template <int F, int STRIDE, int INK>
__global__ __launch_bounds__(256, 5) void edge_mlp_fused_k(
    const ushort_t* __restrict__ feat,
    const uint4* __restrict__ edat,
    const int* __restrict__ offset, const int* __restrict__ count,
    const ushort_t* __restrict__ pw,
    const float* __restrict__ b1, const float* __restrict__ b2,
    float* __restrict__ agg)
{
    constexpr int S1 = INK / 32;
    constexpr int W1ST = INK + 8;
    constexpr int C1ST = C1ST_;
    constexpr int MST = 260;                         // bf16 msg tile stride
    constexpr int ABYTES = (64 * W1ST + 32 * C1ST + 4 * 16 * C1ST) * 2;
    constexpr int BBYTES = 32 * MST * 2;             // msg tile [32 feat][260] bf16
    constexpr int UBYTES = (ABYTES > BBYTES) ? ABYTES : BBYTES;
    constexpr int NU4 = (64 * W1ST + 32 * C1ST) / 8;

    __shared__ __align__(16) char ldsu[UBYTES];
    __shared__ int colLds[256];
    __shared__ unsigned char segStartA[256];
    __shared__ short segEndA[256];                   // negative => complete segment
    __shared__ int segCnt;

    ushort_t* sW1 = (ushort_t*)ldsu;                 // [64][W1ST]
    ushort_t* sW2 = sW1 + 64 * W1ST;                 // [32][C1ST]
    ushort_t* sC1 = sW2 + 32 * C1ST;                 // [4][16][C1ST]
    ushort_t* msgT16 = (ushort_t*)ldsu;              // [32][MST] bf16

    const int tid = threadIdx.x;
    const int B0 = blockIdx.x * 256;
    if (tid == 0) segCnt = 0;
    colLds[tid] = (int)edat[B0 + tid].y;

    // stage pre-packed weights: straight uint4 copy
    {
        const uint4* src = (const uint4*)pw;
        uint4* dst = (uint4*)ldsu;
        for (int i = tid; i < NU4; i += 256) dst[i] = src[i];
    }
    __syncthreads();

    // build segment list (col is sorted within the block)
    {
        bool isStart = (tid == 0) || (colLds[tid] != colLds[tid - 1]);
        if (isStart) {
            int node = colLds[tid];
            int off = offset[node], cn = count[node];
            int e = off + cn - B0; if (e > 256) e = 256;
            bool fullseg = (off >= B0) && (off + cn <= B0 + 256);
            int j = atomicAdd(&segCnt, 1);
            segStartA[j] = (unsigned char)tid;
            segEndA[j] = (short)(fullseg ? -e : e);
        }
    }

    const int wave = tid >> 6, lane = tid & 63;
    const int lr = lane & 15, jb = lane >> 4;
    const size_t slotBase = (size_t)B0 + (size_t)wave * 64;
    const float4* b1v = (const float4*)b1;
    ushort_t* myC1 = sC1 + wave * 16 * C1ST;         // [16][C1ST]
    const float bb2_0 = b2[lr], bb2_1 = b2[16 + lr];

    f32x4 acc2a[4][2];                               // [quarter][n]

#pragma unroll
    for (int q = 0; q < 4; q++) {
        // gather B-fragments for 16 edges
        bf16x8 xf[S1];
        {
            size_t slot = slotBase + (size_t)q * 16 + lr;
            uint4 ed = edat[slot];
            const ushort_t* xr = feat + (size_t)ed.x * STRIDE;
            const ushort_t* xc = feat + (size_t)ed.y * STRIDE;
            xf[0] = *(const bf16x8*)(xr + jb * 8);
            if (F == 37) {
                const ushort_t* p1 = (jb == 0) ? (xr + 32) : (xc + (jb - 1) * 8);
                xf[1] = *(const bf16x8*)p1;
                bf16x8 v;
                if (jb < 2) {
                    v = *(const bf16x8*)((jb == 0) ? (xc + 24) : (xc + 32));
                } else if (jb == 2) {
                    uint4 t = make_uint4(ed.z, ed.w, 0u, 0u);
                    v = __builtin_bit_cast(bf16x8, t);
                } else {
                    uint4 t = make_uint4(0u, 0u, 0u, 0u);
                    v = __builtin_bit_cast(bf16x8, t);
                }
                xf[2] = v;
            } else {
                if (jb < 3) {
                    xf[1] = *(const bf16x8*)(xc + jb * 8);
                } else {
                    uint2 lo = *(const uint2*)(xc + 24);
                    uint4 t = make_uint4(lo.x, lo.y, ed.z, ed.w);
                    xf[1] = __builtin_bit_cast(bf16x8, t);
                }
            }
        }

        // layer 1: D1[hid][edge], bias in C-init
        f32x4 acc1[4];
#pragma unroll
        for (int mh = 0; mh < 4; mh++) {
            float4 bv = b1v[mh * 4 + jb];
            acc1[mh] = f32x4{bv.x, bv.y, bv.z, bv.w};
        }
#pragma unroll
        for (int s = 0; s < S1; s++) {
#pragma unroll
            for (int mh = 0; mh < 4; mh++) {
                bf16x8 wf = *(const bf16x8*)&sW1[(mh * 16 + lr) * W1ST + s * 32 + jb * 8];
                acc1[mh] = MFMA16(wf, xf[s], acc1[mh]);
            }
        }

        // relu -> bf16 -> packed b64 stores into wave-private C1 [16 edges][C1ST]
#pragma unroll
        for (int mh = 0; mh < 4; mh++) {
            f32x4 a = acc1[mh];
            unsigned w0 = pk2(fmaxf(a[0], 0.f), fmaxf(a[1], 0.f));
            unsigned w1 = pk2(fmaxf(a[2], 0.f), fmaxf(a[3], 0.f));
            *(uint2*)&myC1[lr * C1ST + mh * 16 + jb * 4] = make_uint2(w0, w1);
        }

        // layer 2: D2[edge][hid2], bias in C-init
        acc2a[q][0] = f32x4{bb2_0, bb2_0, bb2_0, bb2_0};
        acc2a[q][1] = f32x4{bb2_1, bb2_1, bb2_1, bb2_1};
#pragma unroll
        for (int s2 = 0; s2 < 2; s2++) {
            bf16x8 w2f0 = *(const bf16x8*)&sW2[lr * C1ST + s2 * 32 + jb * 8];
            bf16x8 w2f1 = *(const bf16x8*)&sW2[(16 + lr) * C1ST + s2 * 32 + jb * 8];
            bf16x8 a2 = *(const bf16x8*)&myC1[lr * C1ST + s2 * 32 + jb * 8];
            acc2a[q][0] = MFMA16(a2, w2f0, acc2a[q][0]);
            acc2a[q][1] = MFMA16(a2, w2f1, acc2a[q][1]);
        }
    }

    // all waves done with sW1/sW2/sC1 -> alias the region as the bf16 msg tile
    __syncthreads();
#pragma unroll
    for (int q = 0; q < 4; q++) {
        int row = wave * 64 + q * 16 + jb * 4;       // + r4
#pragma unroll
        for (int n = 0; n < 2; n++) {
            f32x4 a = acc2a[q][n];
            ushort_t* dst = &msgT16[(size_t)(n * 16 + lr) * MST + row];
            *(uint2*)dst = make_uint2(pk2(a[0], a[1]), pk2(a[2], a[3]));
        }
    }
    __syncthreads();

    // per-node reduction: wave w handles segments w, w+4, ...
    {
        int f = lane & 31;
        int h = lane >> 5;
        const ushort_t* mrow = msgT16 + (size_t)f * MST;
        int nseg = segCnt;
        for (int j = wave; j < nseg; j += 4) {
            int s = segStartA[j];
            int ev = segEndA[j];
            bool fullseg = ev < 0;
            int e = fullseg ? -ev : ev;
            int node = colLds[s];
            float sum = 0.f;
            for (int i = s + h; i < e; i += 2) sum += bf2f(mrow[i]);
            sum += __shfl_xor(sum, 32);
            if (lane < 32) {
                float* dst = &agg[(size_t)node * 32 + f];
                if (fullseg) *dst = sum;
                else atomicAdd(dst, sum);
            }
        }
    }
}

// ---------------- edge history LSTM + bf16 padded full table ----------------
__global__ __launch_bounds__(256) void edge_lstm_k(
    const float* __restrict__ agg, const float* __restrict__ cnt,
    const float* __restrict__ h0, const float* __restrict__ c0,
    const float* __restrict__ Wih, const float* __restrict__ Whh,
    const float* __restrict__ bih, const float* __restrict__ bhh,
    const float* __restrict__ node_h,
    float* __restrict__ h_out, float* __restrict__ c_out, ushort_t* __restrict__ full16)
{
    __shared__ float sWih[32 * 32];
    __shared__ float sWhh[32 * 8];
    __shared__ float sb[32];
    for (int i = threadIdx.x; i < 32 * 32; i += 256) sWih[i] = Wih[i];
    for (int i = threadIdx.x; i < 32 * 8; i += 256) sWhh[i] = Whh[i];
    if (threadIdx.x < 32) sb[threadIdx.x] = bih[threadIdx.x] + bhh[threadIdx.x];
    __syncthreads();
    int n = blockIdx.x * 256 + threadIdx.x;
    if (n >= NN) return;

    float inv = 1.0f / fmaxf(cnt[n], 1.0f);
    float msg[32];
#pragma unroll
    for (int k = 0; k < 32; k++) msg[k] = agg[(size_t)n * 32 + k] * inv;
    float h[8];
#pragma unroll
    for (int k = 0; k < 8; k++) h[k] = h0[n * 8 + k];

    float fl[32];
#pragma unroll
    for (int k = 0; k < 20; k++) fl[k] = node_h[n * 20 + k];
    fl[28] = 0.f; fl[29] = 0.f; fl[30] = 0.f; fl[31] = 0.f;

#pragma unroll
    for (int r = 0; r < 8; r++) {
        float gi = sb[r], gf = sb[8 + r], gg = sb[16 + r], go = sb[24 + r];
#pragma unroll
        for (int k = 0; k < 32; k++) {
            float v = msg[k];
            gi = fmaf(v, sWih[r * 32 + k], gi);
            gf = fmaf(v, sWih[(8 + r) * 32 + k], gf);
            gg = fmaf(v, sWih[(16 + r) * 32 + k], gg);
            go = fmaf(v, sWih[(24 + r) * 32 + k], go);
        }
#pragma unroll
        for (int k = 0; k < 8; k++) {
            float v = h[k];
            gi = fmaf(v, sWhh[r * 8 + k], gi);
            gf = fmaf(v, sWhh[(8 + r) * 8 + k], gf);
            gg = fmaf(v, sWhh[(16 + r) * 8 + k], gg);
            go = fmaf(v, sWhh[(24 + r) * 8 + k], go);
        }
        float cr = c0[n * 8 + r];
        float cn = sigmoidf_(gf) * cr + sigmoidf_(gi) * tanhf(gg);
        float hn = sigmoidf_(go) * tanhf(cn);
        h_out[n * 8 + r] = hn;
        c_out[n * 8 + r] = cn;
        fl[20 + r] = hn;
    }
    unsigned w[16];
#pragma unroll
    for (int k = 0; k < 16; k++) w[k] = pk2(fl[2 * k], fl[2 * k + 1]);
    uint4* dst = (uint4*)(full16 + (size_t)n * 32);
#pragma unroll
    for (int q = 0; q < 4; q++)
        dst[q] = make_uint4(w[q * 4], w[q * 4 + 1], w[q * 4 + 2], w[q * 4 + 3]);
}

// ---------------- output node MLP (reads bf16 full) ----------------
__global__ __launch_bounds__(256) void node_out_k(
    const ushort_t* __restrict__ full16, const float* __restrict__ agg2, const float* __restrict__ cnt,
    const float* __restrict__ W1, const float* __restrict__ b1,
    const float* __restrict__ W2, const float* __restrict__ b2,
    float* __restrict__ out)
{
    __shared__ __align__(16) float sW1[60 * 64];
    __shared__ __align__(16) float sW2[64 * 4];
    __shared__ float sb1[64];
    __shared__ float sb2[4];
    for (int i = threadIdx.x; i < 60 * 64; i += 256) sW1[i] = W1[i];
    for (int i = threadIdx.x; i < 64 * 4; i += 256) sW2[i] = W2[i];
    if (threadIdx.x < 64) sb1[threadIdx.x] = b1[threadIdx.x];
    if (threadIdx.x < 4) sb2[threadIdx.x] = b2[threadIdx.x];
    __syncthreads();
    int n = blockIdx.x * 256 + threadIdx.x;
    if (n >= NN) return;

    float in[60];
    const ushort_t* fr = full16 + (size_t)n * 32;
#pragma unroll
    for (int k = 0; k < 28; k++) in[k] = bf2f(fr[k]);
    float inv = 1.0f / fmaxf(cnt[n], 1.0f);
#pragma unroll
    for (int k = 0; k < 32; k++) in[28 + k] = agg2[(size_t)n * 32 + k] * inv;

    float o[4] = {sb2[0], sb2[1], sb2[2], sb2[3]};
#pragma unroll 1
    for (int j = 0; j < 64; j += 4) {
        float s[4] = {sb1[j], sb1[j + 1], sb1[j + 2], sb1[j + 3]};
#pragma unroll
        for (int k = 0; k < 60; k++) {
            float4 w = *(const float4*)&sW1[k * 64 + j];
            s[0] = fmaf(in[k], w.x, s[0]);
            s[1] = fmaf(in[k], w.y, s[1]);
            s[2] = fmaf(in[k], w.z, s[2]);
            s[3] = fmaf(in[k], w.w, s[3]);
        }
#pragma unroll
        for (int jj = 0; jj < 4; jj++) {
            float sv = fmaxf(s[jj], 0.0f);
            float4 w = *(const float4*)&sW2[(j + jj) * 4];
            o[0] = fmaf(sv, w.x, o[0]);
            o[1] = fmaf(sv, w.y, o[1]);
            o[2] = fmaf(sv, w.z, o[2]);
            o[3] = fmaf(sv, w.w, o[3]);
        }
    }
#pragma unroll
    for (int m = 0; m < 4; m++) out[n * 4 + m] = o[m];
}

// ---------------- fallback atomic edge MLP (reads bf16 tables) ----------------
template <int F, int STRIDE, bool DO_CNT>
__global__ __launch_bounds__(256) void edge_mlp_atomic_k(
    const ushort_t* __restrict__ feat,
    const int* __restrict__ row, const int* __restrict__ col,
    const float* __restrict__ eattr,
    const float* __restrict__ W1, const float* __restrict__ b1,
    const float* __restrict__ W2, const float* __restrict__ b2,
    float* __restrict__ agg, float* __restrict__ cnt)
{
    constexpr int IN = 2 * F + 4;
    __shared__ __align__(16) float sW1[IN * 64];
    __shared__ __align__(16) float sW2[64 * 32];
    __shared__ float sb1[64];
    __shared__ float sb2[32];
    for (int i = threadIdx.x; i < IN * 64; i += 256) sW1[i] = W1[i];
    for (int i = threadIdx.x; i < 64 * 32; i += 256) sW2[i] = W2[i];
    if (threadIdx.x < 64) sb1[threadIdx.x] = b1[threadIdx.x];
    if (threadIdx.x < 32) sb2[threadIdx.x] = b2[threadIdx.x];
    __syncthreads();
    int e = blockIdx.x * 256 + threadIdx.x;
    if (e >= EE) return;

    int r = row[e], c = col[e];
    float h[IN];
#pragma unroll
    for (int k = 0; k < F; k++) h[k] = bf2f(feat[(size_t)r * STRIDE + k]);
#pragma unroll
    for (int k = 0; k < F; k++) h[F + k] = bf2f(feat[(size_t)c * STRIDE + k]);
    float4 ev = *(const float4*)&eattr[(size_t)e * 4];
    h[2 * F] = ev.x; h[2 * F + 1] = ev.y; h[2 * F + 2] = ev.z; h[2 * F + 3] = ev.w;

    float out[32];
#pragma unroll
    for (int m = 0; m < 32; m++) out[m] = sb2[m];
#pragma unroll 1
    for (int j = 0; j < 64; j += 4) {
        float s[4] = {sb1[j], sb1[j + 1], sb1[j + 2], sb1[j + 3]};
#pragma unroll
        for (int k = 0; k < IN; k++) {
            float4 w = *(const float4*)&sW1[k * 64 + j];
            s[0] = fmaf(h[k], w.x, s[0]);
            s[1] = fmaf(h[k], w.y, s[1]);
            s[2] = fmaf(h[k], w.z, s[2]);
            s[3] = fmaf(h[k], w.w, s[3]);
        }
        s[0] = fmaxf(s[0], 0.f); s[1] = fmaxf(s[1], 0.f);
        s[2] = fmaxf(s[2], 0.f); s[3] = fmaxf(s[3], 0.f);
#pragma unroll
        for (int jj = 0; jj < 4; jj++) {
#pragma unroll
            for (int m = 0; m < 32; m += 4) {
                float4 w = *(const float4*)&sW2[(j + jj) * 32 + m];
                out[m]     = fmaf(s[jj], w.x, out[m]);
                out[m + 1] = fmaf(s[jj], w.y, out[m + 1]);
                out[m + 2] = fmaf(s[jj], w.z, out[m + 2]);
                out[m + 3] = fmaf(s[jj], w.w, out[m + 3]);
            }
        }
    }
    float* dst = &agg[(size_t)c * 32];
#pragma unroll
    for (int m = 0; m < 32; m++) atomicAdd(&dst[m], out[m]);
    if (DO_CNT) atomicAdd(&cnt[c], 1.0f);
}

extern "C" void kernel_launch(void* const* d_in, const int* in_sizes, int n_in,
                              void* d_out, int out_size, void* d_ws, size_t ws_size,
                              hipStream_t stream) {
    (void)in_sizes; (void)n_in; (void)out_size;
    const float* x      = (const float*)d_in[0];
    const float* u      = (const float*)d_in[1];
    const int*   ei     = (const int*)d_in[2];
    const float* eattr  = (const float*)d_in[3];
    const float* hn_h   = (const float*)d_in[4];
    const float* hn_c   = (const float*)d_in[5];
    const float* he_h   = (const float*)d_in[6];
    const float* he_c   = (const float*)d_in[7];
    const float* Wih_n  = (const float*)d_in[8];
    const float* Whh_n  = (const float*)d_in[9];
    const float* bih_n  = (const float*)d_in[10];
    const float* bhh_n  = (const float*)d_in[11];
    const float* Wih_e  = (const float*)d_in[12];
    const float* Whh_e  = (const float*)d_in[13];
    const float* bih_e  = (const float*)d_in[14];
    const float* bhh_e  = (const float*)d_in[15];
    const float* We1    = (const float*)d_in[16];
    const float* be1    = (const float*)d_in[17];
    const float* We2    = (const float*)d_in[18];
    const float* be2    = (const float*)d_in[19];
    const float* Wo1    = (const float*)d_in[20];
    const float* bo1    = (const float*)d_in[21];
    const float* Wo2    = (const float*)d_in[22];
    const float* bo2    = (const float*)d_in[23];
    const float* Wn1    = (const float*)d_in[24];
    const float* bn1    = (const float*)d_in[25];
    const float* Wn2    = (const float*)d_in[26];
    const float* bn2    = (const float*)d_in[27];

    const int* row = ei;
    const int* col = ei + EE;

    float* out = (float*)d_out;
    float* out_y   = out;                        // [N,4]
    float* node_h  = out + (size_t)NN * 4;       // [N,20]
    float* node_c  = out + (size_t)NN * 24;      // [N,20]
    float* edge_h  = out + (size_t)NN * 44;      // [N,8]
    float* edge_c  = out + (size_t)NN * 52;      // [N,8]

    int nb_n = (NN + 255) / 256;
    int nb_e = (EE + 255) / 256;

    // ---- workspace layout ----
    ushort_t* xu16   = (ushort_t*)d_ws;
    ushort_t* full16 = xu16 + (size_t)NN * 40;
    float* agg  = (float*)(full16 + (size_t)NN * 32);
    float* cntf = agg + (size_t)NN * 32;
    float* agg2 = cntf + NN;
    int* count  = (int*)(agg2 + (size_t)NN * 32);
    int* cursor = count + NN;
    int* offset = cursor + NN;
    int* bsum   = offset + NN;
    int* bpre   = bsum + SBLK;
    size_t pw_off = ((size_t)((char*)(bpre + SBLK) - (char*)d_ws) + 15) & ~(size_t)15;
    ushort_t* pw = (ushort_t*)((char*)d_ws + pw_off);
    size_t edat_off = ((pw_off + (size_t)(PW1A + PW2A + PW1B + PW2B) * 2) + 15) & ~(size_t)15;
    uint4* edat = (uint4*)((char*)d_ws + edat_off);
    size_t needed = edat_off + (size_t)EE * 16;

    if (ws_size >= needed) {
        // zero agg | cntf | agg2 | count | cursor in one contiguous memset
        hipError_t _e = hipMemsetAsync(agg, 0, (size_t)NN * (32 + 1 + 32 + 1 + 1) * sizeof(float), stream);
        (void)_e;

        pack_w_k<<<1, 256, 0, stream>>>(We1, We2, Wo1, Wo2, pw);
        node_lstm_k<<<nb_n, 256, 0, stream>>>(x, u, hn_h, hn_c, Wih_n, Whh_n, bih_n, bhh_n,
                                              xu16, node_h, node_c);
        csr_count_k<<<nb_e, 256, 0, stream>>>(col, count);
        scan1_k<<<SBLK, 256, 0, stream>>>(count, bsum);
        scan2_k<<<1, 256, 0, stream>>>(bsum, bpre);
        scan3_k<<<SBLK, 256, 0, stream>>>(count, bpre, offset, cntf);
        csr_fill4_k<<<nb_e, 256, 0, stream>>>(row, col, eattr, offset, cursor, edat);

        edge_mlp_fused_k<37, 40, 96><<<EE / 256, 256, 0, stream>>>(
            xu16, edat, offset, count, pw, be1, be2, agg);
        edge_lstm_k<<<nb_n, 256, 0, stream>>>(agg, cntf, he_h, he_c, Wih_e, Whh_e, bih_e, bhh_e,
                                              node_h, edge_h, edge_c, full16);
        edge_mlp_fused_k<28, 32, 64><<<EE / 256, 256, 0, stream>>>(
            full16, edat, offset, count, pw + PW1A + PW2A, bo1, bo2, agg2);
        node_out_k<<<nb_n, 256, 0, stream>>>(full16, agg2, cntf, Wn1, bn1, Wn2, bn2, out_y);
    } else {
        // fallback: atomic scatter path
        hipError_t _e = hipMemsetAsync(agg, 0, (size_t)NN * (32 + 1 + 32) * sizeof(float), stream);
        (void)_e;
        node_lstm_k<<<nb_n, 256, 0, stream>>>(x, u, hn_h, hn_c, Wih_n, Whh_n, bih_n, bhh_n,
                                              xu16, node_h, node_c);
        edge_mlp_atomic_k<37, 40, true><<<nb_e, 256, 0, stream>>>(xu16, row, col, eattr,
                                                                  We1, be1, We2, be2, agg, cntf);
        edge_lstm_k<<<nb_n, 256, 0, stream>>>(agg, cntf, he_h, he_c, Wih_e, Whh_e, bih_e, bhh_e,
                                              node_h, edge_h, edge_c, full16);
        edge_mlp_atomic_k<28, 32, false><<<nb_e, 256, 0, stream>>>(full16, row, col, eattr,
                                                                   Wo1, bo1, Wo2, bo2, agg2, nullptr);
        node_out_k<<<nb_n, 256, 0, stream>>>(full16, agg2, cntf, Wn1, bn1, Wn2, bn2, out_y);
    }
}

// Round 16
// 248.920 us; speedup vs baseline: 1.1069x; 1.0312x over previous
//
#include <hip/hip_runtime.h>
#include <math.h>

#define NN 50000
#define EE 800000
#define SBLK ((NN + 255) / 256)   // 196 scan blocks

typedef short bf16x8 __attribute__((ext_vector_type(8)));
typedef float f32x4 __attribute__((ext_vector_type(4)));
typedef unsigned short ushort_t;
#define MFMA16(a, b, c) __builtin_amdgcn_mfma_f32_16x16x32_bf16(a, b, c, 0, 0, 0)

__device__ __forceinline__ float sigmoidf_(float x) { return 1.0f / (1.0f + __expf(-x)); }

__device__ __forceinline__ unsigned short f2bf(float f) {
    unsigned u = __builtin_bit_cast(unsigned, f);
    u += 0x7FFFu + ((u >> 16) & 1u);
    return (unsigned short)(u >> 16);
}
__device__ __forceinline__ float bf2f(unsigned short v) {
    unsigned u = (unsigned)v << 16;
    return __builtin_bit_cast(float, u);
}
__device__ __forceinline__ unsigned pk2(float a, float b) {
    return ((unsigned)f2bf(b) << 16) | (unsigned)f2bf(a);
}

// packed bf16 weight table sizes (bf16 elements)
#define W1ST_A 104   // INK=96 + 8
#define W1ST_B 72    // INK=64 + 8
#define C1ST_  72
#define PW1A (64 * W1ST_A)
#define PW2A (32 * C1ST_)
#define PW1B (64 * W1ST_B)
#define PW2B (32 * C1ST_)

// ---------------- pre-pack both edge-MLP weight sets to bf16 LDS layout ----------------
__global__ __launch_bounds__(256) void pack_w_k(
    const float* __restrict__ We1, const float* __restrict__ We2,
    const float* __restrict__ Wo1, const float* __restrict__ Wo2,
    ushort_t* __restrict__ pw)
{
    ushort_t* pw1a = pw;
    ushort_t* pw2a = pw1a + PW1A;
    ushort_t* pw1b = pw2a + PW2A;
    ushort_t* pw2b = pw1b + PW1B;
    int tid = threadIdx.x;

    for (int i = tid; i < PW1A; i += 256) {
        int n = i / W1ST_A, nk = i - n * W1ST_A;
        int kp = 0; bool z = false;
        if (nk < 37) kp = nk;
        else if (nk < 40) z = true;
        else if (nk < 77) kp = nk - 3;
        else if (nk < 80) z = true;
        else if (nk < 84) kp = nk - 6;
        else z = true;
        pw1a[i] = z ? (ushort_t)0 : f2bf(We1[kp * 64 + n]);
    }
    for (int i = tid; i < PW2A; i += 256) {
        int n = i / C1ST_, k = i - n * C1ST_;
        pw2a[i] = (k < 64) ? f2bf(We2[k * 32 + n]) : (ushort_t)0;
    }
    for (int i = tid; i < PW1B; i += 256) {
        int n = i / W1ST_B, nk = i - n * W1ST_B;
        int kp = 0; bool z = false;
        if (nk < 28) kp = nk;
        else if (nk < 32) z = true;
        else if (nk < 64) kp = nk - 4;
        else z = true;
        pw1b[i] = z ? (ushort_t)0 : f2bf(Wo1[kp * 64 + n]);
    }
    for (int i = tid; i < PW2B; i += 256) {
        int n = i / C1ST_, k = i - n * C1ST_;
        pw2b[i] = (k < 64) ? f2bf(Wo2[k * 32 + n]) : (ushort_t)0;
    }
}

// ---------------- node history LSTM + bf16 padded xu table ----------------
// 4 threads per node (64 nodes/block); thread qr computes gate rows r=5qr..5qr+4.
__global__ __launch_bounds__(256) void node_lstm_k(
    const float* __restrict__ x, const float* __restrict__ u,
    const float* __restrict__ h0, const float* __restrict__ c0,
    const float* __restrict__ Wih, const float* __restrict__ Whh,
    const float* __restrict__ bih, const float* __restrict__ bhh,
    ushort_t* __restrict__ xu16, float* __restrict__ h_out, float* __restrict__ c_out)
{
    __shared__ float sWih[80 * 37];
    __shared__ float sWhh[80 * 20];
    __shared__ float sb[80];
    for (int i = threadIdx.x; i < 80 * 37; i += 256) sWih[i] = Wih[i];
    for (int i = threadIdx.x; i < 80 * 20; i += 256) sWhh[i] = Whh[i];
    if (threadIdx.x < 80) sb[threadIdx.x] = bih[threadIdx.x] + bhh[threadIdx.x];
    __syncthreads();

    int nl = threadIdx.x >> 2;        // node within block
    int qr = threadIdx.x & 3;         // gate-row quarter
    int n = blockIdx.x * 64 + nl;
    if (n >= NN) return;

    float xu[40];
#pragma unroll
    for (int k = 0; k < 5; k++) xu[k] = x[n * 5 + k];
#pragma unroll
    for (int k = 0; k < 32; k++) xu[5 + k] = u[n * 32 + k];
    xu[37] = 0.f; xu[38] = 0.f; xu[39] = 0.f;

    if (qr == 0) {
        unsigned w[20];
#pragma unroll
        for (int k = 0; k < 20; k++) w[k] = pk2(xu[2 * k], xu[2 * k + 1]);
        uint4* dst = (uint4*)(xu16 + (size_t)n * 40);
#pragma unroll
        for (int q = 0; q < 5; q++)
            dst[q] = make_uint4(w[q * 4], w[q * 4 + 1], w[q * 4 + 2], w[q * 4 + 3]);
    }

    float h[20];
#pragma unroll
    for (int k = 0; k < 20; k++) h[k] = h0[n * 20 + k];

    float hb[5], cb[5];
#pragma unroll 1
    for (int rr = 0; rr < 5; rr++) {
        int r = qr * 5 + rr;
        float gi = sb[r], gf = sb[20 + r], gg = sb[40 + r], go = sb[60 + r];
#pragma unroll
        for (int k = 0; k < 37; k++) {
            float v = xu[k];
            gi = fmaf(v, sWih[r * 37 + k], gi);
            gf = fmaf(v, sWih[(20 + r) * 37 + k], gf);
            gg = fmaf(v, sWih[(40 + r) * 37 + k], gg);
            go = fmaf(v, sWih[(60 + r) * 37 + k], go);
        }
#pragma unroll
        for (int k = 0; k < 20; k++) {
            float v = h[k];
            gi = fmaf(v, sWhh[r * 20 + k], gi);
            gf = fmaf(v, sWhh[(20 + r) * 20 + k], gf);
            gg = fmaf(v, sWhh[(40 + r) * 20 + k], gg);
            go = fmaf(v, sWhh[(60 + r) * 20 + k], go);
        }
        float cr = c0[n * 20 + r];
        float cn = sigmoidf_(gf) * cr + sigmoidf_(gi) * tanhf(gg);
        float hn = sigmoidf_(go) * tanhf(cn);
        hb[rr] = hn;
        cb[rr] = cn;
    }
#pragma unroll
    for (int rr = 0; rr < 5; rr++) {
        h_out[n * 20 + qr * 5 + rr] = hb[rr];
        c_out[n * 20 + qr * 5 + rr] = cb[rr];
    }
}

// ---------------- CSR build ----------------
__global__ __launch_bounds__(256) void csr_count_k(const int* __restrict__ col,
                                                   int* __restrict__ count)
{
    int e = blockIdx.x * 256 + threadIdx.x;
    if (e < EE) atomicAdd(&count[col[e]], 1);
}

__global__ __launch_bounds__(256) void scan1_k(const int* __restrict__ count,
                                               int* __restrict__ bsum)
{
    __shared__ int red[256];
    int t = threadIdx.x;
    int i = blockIdx.x * 256 + t;
    red[t] = (i < NN) ? count[i] : 0;
    __syncthreads();
#pragma unroll
    for (int d = 128; d > 0; d >>= 1) {
        if (t < d) red[t] += red[t + d];
        __syncthreads();
    }
    if (t == 0) bsum[blockIdx.x] = red[0];
}

__global__ __launch_bounds__(256) void scan2_k(const int* __restrict__ bsum,
                                               int* __restrict__ bpre)
{
    __shared__ int s[256];
    int t = threadIdx.x;
    int v = (t < SBLK) ? bsum[t] : 0;
    s[t] = v;
    __syncthreads();
#pragma unroll
    for (int d = 1; d < 256; d <<= 1) {
        int w = (t >= d) ? s[t - d] : 0;
        __syncthreads();
        s[t] += w;
        __syncthreads();
    }
    if (t < SBLK) bpre[t] = s[t] - v;
}

__global__ __launch_bounds__(256) void scan3_k(const int* __restrict__ count,
                                               const int* __restrict__ bpre,
                                               int* __restrict__ offset,
                                               float* __restrict__ cntf)
{
    __shared__ int s[256];
    int t = threadIdx.x;
    int i = blockIdx.x * 256 + t;
    int v = (i < NN) ? count[i] : 0;
    s[t] = v;
    __syncthreads();
#pragma unroll
    for (int d = 1; d < 256; d <<= 1) {
        int w = (t >= d) ? s[t - d] : 0;
        __syncthreads();
        s[t] += w;
        __syncthreads();
    }
    if (i < NN) {
        offset[i] = bpre[blockIdx.x] + s[t] - v;
        cntf[i] = (float)v;
    }
}

// fill CSR: one packed uint4 {row, col, ea01, ea23} per slot
__global__ __launch_bounds__(256) void csr_fill4_k(const int* __restrict__ row,
                                                   const int* __restrict__ col,
                                                   const float* __restrict__ eattr,
                                                   const int* __restrict__ offset,
                                                   int* __restrict__ cursor,
                                                   uint4* __restrict__ edat)
{
    int e = blockIdx.x * 256 + threadIdx.x;
    if (e >= EE) return;
    int c = col[e];
    int pos = atomicAdd(&cursor[c], 1);
    int slot = offset[c] + pos;
    float4 ev = *(const float4*)&eattr[(size_t)e * 4];
    edat[slot] = make_uint4((unsigned)row[e], (unsigned)c, pk2(ev.x, ev.y), pk2(ev.z, ev.w));
}

// ---------------- fused 2-layer edge MLP + in-block segment sum ----------------
template <int F, int STRIDE, int INK>
__global__ __launch_bounds__(256, 5) void edge_mlp_fused_k(
    const ushort_t* __restrict__ feat,
    const uint4* __restrict__ edat,
    const int* __restrict__ offset, const int* __restrict__ count,
    const ushort_t* __restrict__ pw,
    const float* __restrict__ b1, const float* __restrict__ b2,
    float* __restrict__ agg)
{
    constexpr int S1 = INK / 32;
    constexpr int W1ST = INK + 8;
    constexpr int C1ST = C1ST_;
    constexpr int MST = 260;                         // bf16 msg tile stride
    constexpr int ABYTES = (64 * W1ST + 32 * C1ST + 4 * 16 * C1ST) * 2;
    constexpr int BBYTES = 32 * MST * 2;             // msg tile [32 feat][260] bf16
    constexpr int UBYTES = (ABYTES > BBYTES) ? ABYTES : BBYTES;
    constexpr int NU4 = (64 * W1ST + 32 * C1ST) / 8;

    __shared__ __align__(16) char ldsu[UBYTES];
    __shared__ int colLds[256];
    __shared__ unsigned char segStartA[256];
    __shared__ short segEndA[256];                   // negative => complete segment
    __shared__ int segCnt;

    ushort_t* sW1 = (ushort_t*)ldsu;                 // [64][W1ST]
    ushort_t* sW2 = sW1 + 64 * W1ST;                 // [32][C1ST]
    ushort_t* sC1 = sW2 + 32 * C1ST;                 // [4][16][C1ST]
    ushort_t* msgT16 = (ushort_t*)ldsu;              // [32][MST] bf16

    const int tid = threadIdx.x;
    const int B0 = blockIdx.x * 256;
    if (tid == 0) segCnt = 0;
    colLds[tid] = (int)edat[B0 + tid].y;

    // stage pre-packed weights: straight uint4 copy
    {
        const uint4* src = (const uint4*)pw;
        uint4* dst = (uint4*)ldsu;
        for (int i = tid; i < NU4; i += 256) dst[i] = src[i];
    }
    __syncthreads();

    // build segment list (col is sorted within the block)
    {
        bool isStart = (tid == 0) || (colLds[tid] != colLds[tid - 1]);
        if (isStart) {
            int node = colLds[tid];
            int off = offset[node], cn = count[node];
            int e = off + cn - B0; if (e > 256) e = 256;
            bool fullseg = (off >= B0) && (off + cn <= B0 + 256);
            int j = atomicAdd(&segCnt, 1);
            segStartA[j] = (unsigned char)tid;
            segEndA[j] = (short)(fullseg ? -e : e);
        }
    }

    const int wave = tid >> 6, lane = tid & 63;
    const int lr = lane & 15, jb = lane >> 4;
    const size_t slotBase = (size_t)B0 + (size_t)wave * 64;
    const float4* b1v = (const float4*)b1;
    ushort_t* myC1 = sC1 + wave * 16 * C1ST;         // [16][C1ST]
    const float bb2_0 = b2[lr], bb2_1 = b2[16 + lr];

    f32x4 acc2a[4][2];                               // [quarter][n]

#pragma unroll
    for (int q = 0; q < 4; q++) {
        // gather B-fragments for 16 edges
        bf16x8 xf[S1];
        {
            size_t slot = slotBase + (size_t)q * 16 + lr;
            uint4 ed = edat[slot];
            const ushort_t* xr = feat + (size_t)ed.x * STRIDE;
            const ushort_t* xc = feat + (size_t)ed.y * STRIDE;
            xf[0] = *(const bf16x8*)(xr + jb * 8);
            if (F == 37) {
                const ushort_t* p1 = (jb == 0) ? (xr + 32) : (xc + (jb - 1) * 8);
                xf[1] = *(const bf16x8*)p1;
                bf16x8 v;
                if (jb < 2) {
                    v = *(const bf16x8*)((jb == 0) ? (xc + 24) : (xc + 32));
                } else if (jb == 2) {
                    uint4 t = make_uint4(ed.z, ed.w, 0u, 0u);
                    v = __builtin_bit_cast(bf16x8, t);
                } else {
                    uint4 t = make_uint4(0u, 0u, 0u, 0u);
                    v = __builtin_bit_cast(bf16x8, t);
                }
                xf[2] = v;
            } else {
                if (jb < 3) {
                    xf[1] = *(const bf16x8*)(xc + jb * 8);
                } else {
                    uint2 lo = *(const uint2*)(xc + 24);
                    uint4 t = make_uint4(lo.x, lo.y, ed.z, ed.w);
                    xf[1] = __builtin_bit_cast(bf16x8, t);
                }
            }
        }

        // layer 1: D1[hid][edge], bias in C-init
        f32x4 acc1[4];
#pragma unroll
        for (int mh = 0; mh < 4; mh++) {
            float4 bv = b1v[mh * 4 + jb];
            acc1[mh] = f32x4{bv.x, bv.y, bv.z, bv.w};
        }
#pragma unroll
        for (int s = 0; s < S1; s++) {
#pragma unroll
            for (int mh = 0; mh < 4; mh++) {
                bf16x8 wf = *(const bf16x8*)&sW1[(mh * 16 + lr) * W1ST + s * 32 + jb * 8];
                acc1[mh] = MFMA16(wf, xf[s], acc1[mh]);
            }
        }

        // relu -> bf16 -> packed b64 stores into wave-private C1 [16 edges][C1ST]
#pragma unroll
        for (int mh = 0; mh < 4; mh++) {
            f32x4 a = acc1[mh];
            unsigned w0 = pk2(fmaxf(a[0], 0.f), fmaxf(a[1], 0.f));
            unsigned w1 = pk2(fmaxf(a[2], 0.f), fmaxf(a[3], 0.f));
            *(uint2*)&myC1[lr * C1ST + mh * 16 + jb * 4] = make_uint2(w0, w1);
        }

        // layer 2: D2[edge][hid2], bias in C-init
        acc2a[q][0] = f32x4{bb2_0, bb2_0, bb2_0, bb2_0};
        acc2a[q][1] = f32x4{bb2_1, bb2_1, bb2_1, bb2_1};
#pragma unroll
        for (int s2 = 0; s2 < 2; s2++) {
            bf16x8 w2f0 = *(const bf16x8*)&sW2[lr * C1ST + s2 * 32 + jb * 8];
            bf16x8 w2f1 = *(const bf16x8*)&sW2[(16 + lr) * C1ST + s2 * 32 + jb * 8];
            bf16x8 a2 = *(const bf16x8*)&myC1[lr * C1ST + s2 * 32 + jb * 8];
            acc2a[q][0] = MFMA16(a2, w2f0, acc2a[q][0]);
            acc2a[q][1] = MFMA16(a2, w2f1, acc2a[q][1]);
        }
    }

    // all waves done with sW1/sW2/sC1 -> alias the region as the bf16 msg tile
    __syncthreads();
#pragma unroll
    for (int q = 0; q < 4; q++) {
        int row = wave * 64 + q * 16 + jb * 4;       // + r4
#pragma unroll
        for (int n = 0; n < 2; n++) {
            f32x4 a = acc2a[q][n];
            ushort_t* dst = &msgT16[(size_t)(n * 16 + lr) * MST + row];
            *(uint2*)dst = make_uint2(pk2(a[0], a[1]), pk2(a[2], a[3]));
        }
    }
    __syncthreads();

    // per-node reduction: wave w handles segments w, w+4, ...
    {
        int f = lane & 31;
        int h = lane >> 5;
        const ushort_t* mrow = msgT16 + (size_t)f * MST;
        int nseg = segCnt;
        for (int j = wave; j < nseg; j += 4) {
            int s = segStartA[j];
            int ev = segEndA[j];
            bool fullseg = ev < 0;
            int e = fullseg ? -ev : ev;
            int node = colLds[s];
            float sum = 0.f;
            for (int i = s + h; i < e; i += 2) sum += bf2f(mrow[i]);
            sum += __shfl_xor(sum, 32);
            if (lane < 32) {
                float* dst = &agg[(size_t)node * 32 + f];
                if (fullseg) *dst = sum;
                else atomicAdd(dst, sum);
            }
        }
    }
}

// ---------------- edge history LSTM + bf16 padded full table ----------------
__global__ __launch_bounds__(256) void edge_lstm_k(
    const float* __restrict__ agg, const float* __restrict__ cnt,
    const float* __restrict__ h0, const float* __restrict__ c0,
    const float* __restrict__ Wih, const float* __restrict__ Whh,
    const float* __restrict__ bih, const float* __restrict__ bhh,
    const float* __restrict__ node_h,
    float* __restrict__ h_out, float* __restrict__ c_out, ushort_t* __restrict__ full16)
{
    __shared__ float sWih[32 * 32];
    __shared__ float sWhh[32 * 8];
    __shared__ float sb[32];
    for (int i = threadIdx.x; i < 32 * 32; i += 256) sWih[i] = Wih[i];
    for (int i = threadIdx.x; i < 32 * 8; i += 256) sWhh[i] = Whh[i];
    if (threadIdx.x < 32) sb[threadIdx.x] = bih[threadIdx.x] + bhh[threadIdx.x];
    __syncthreads();
    int n = blockIdx.x * 256 + threadIdx.x;
    if (n >= NN) return;

    float inv = 1.0f / fmaxf(cnt[n], 1.0f);
    float msg[32];
#pragma unroll
    for (int k = 0; k < 32; k++) msg[k] = agg[(size_t)n * 32 + k] * inv;
    float h[8];
#pragma unroll
    for (int k = 0; k < 8; k++) h[k] = h0[n * 8 + k];

    float fl[32];
#pragma unroll
    for (int k = 0; k < 20; k++) fl[k] = node_h[n * 20 + k];
    fl[28] = 0.f; fl[29] = 0.f; fl[30] = 0.f; fl[31] = 0.f;

    float cn_a[8];
#pragma unroll
    for (int r = 0; r < 8; r++) {
        float gi = sb[r], gf = sb[8 + r], gg = sb[16 + r], go = sb[24 + r];
#pragma unroll
        for (int k = 0; k < 32; k++) {
            float v = msg[k];
            gi = fmaf(v, sWih[r * 32 + k], gi);
            gf = fmaf(v, sWih[(8 + r) * 32 + k], gf);
            gg = fmaf(v, sWih[(16 + r) * 32 + k], gg);
            go = fmaf(v, sWih[(24 + r) * 32 + k], go);
        }
#pragma unroll
        for (int k = 0; k < 8; k++) {
            float v = h[k];
            gi = fmaf(v, sWhh[r * 8 + k], gi);
            gf = fmaf(v, sWhh[(8 + r) * 8 + k], gf);
            gg = fmaf(v, sWhh[(16 + r) * 8 + k], gg);
            go = fmaf(v, sWhh[(24 + r) * 8 + k], go);
        }
        float cr = c0[n * 8 + r];
        float cn = sigmoidf_(gf) * cr + sigmoidf_(gi) * tanhf(gg);
        float hn = sigmoidf_(go) * tanhf(cn);
        cn_a[r] = cn;
        fl[20 + r] = hn;
    }
    // coalesced vector stores
    *(float4*)&h_out[n * 8]     = make_float4(fl[20], fl[21], fl[22], fl[23]);
    *(float4*)&h_out[n * 8 + 4] = make_float4(fl[24], fl[25], fl[26], fl[27]);
    *(float4*)&c_out[n * 8]     = make_float4(cn_a[0], cn_a[1], cn_a[2], cn_a[3]);
    *(float4*)&c_out[n * 8 + 4] = make_float4(cn_a[4], cn_a[5], cn_a[6], cn_a[7]);

    unsigned w[16];
#pragma unroll
    for (int k = 0; k < 16; k++) w[k] = pk2(fl[2 * k], fl[2 * k + 1]);
    uint4* dst = (uint4*)(full16 + (size_t)n * 32);
#pragma unroll
    for (int q = 0; q < 4; q++)
        dst[q] = make_uint4(w[q * 4], w[q * 4 + 1], w[q * 4 + 2], w[q * 4 + 3]);
}

// ---------------- output node MLP (reads bf16 full) ----------------
__global__ __launch_bounds__(256) void node_out_k(
    const ushort_t* __restrict__ full16, const float* __restrict__ agg2, const float* __restrict__ cnt,
    const float* __restrict__ W1, const float* __restrict__ b1,
    const float* __restrict__ W2, const float* __restrict__ b2,
    float* __restrict__ out)
{
    __shared__ __align__(16) float sW1[60 * 64];
    __shared__ __align__(16) float sW2[64 * 4];
    __shared__ float sb1[64];
    __shared__ float sb2[4];
    for (int i = threadIdx.x; i < 60 * 64; i += 256) sW1[i] = W1[i];
    for (int i = threadIdx.x; i < 64 * 4; i += 256) sW2[i] = W2[i];
    if (threadIdx.x < 64) sb1[threadIdx.x] = b1[threadIdx.x];
    if (threadIdx.x < 4) sb2[threadIdx.x] = b2[threadIdx.x];
    __syncthreads();
    int n = blockIdx.x * 256 + threadIdx.x;
    if (n >= NN) return;

    float in[60];
    const ushort_t* fr = full16 + (size_t)n * 32;
#pragma unroll
    for (int k = 0; k < 28; k++) in[k] = bf2f(fr[k]);
    float inv = 1.0f / fmaxf(cnt[n], 1.0f);
#pragma unroll
    for (int k = 0; k < 32; k++) in[28 + k] = agg2[(size_t)n * 32 + k] * inv;

    float o[4] = {sb2[0], sb2[1], sb2[2], sb2[3]};
#pragma unroll 1
    for (int j = 0; j < 64; j += 4) {
        float s[4] = {sb1[j], sb1[j + 1], sb1[j + 2], sb1[j + 3]};
#pragma unroll
        for (int k = 0; k < 60; k++) {
            float4 w = *(const float4*)&sW1[k * 64 + j];
            s[0] = fmaf(in[k], w.x, s[0]);
            s[1] = fmaf(in[k], w.y, s[1]);
            s[2] = fmaf(in[k], w.z, s[2]);
            s[3] = fmaf(in[k], w.w, s[3]);
        }
#pragma unroll
        for (int jj = 0; jj < 4; jj++) {
            float sv = fmaxf(s[jj], 0.0f);
            float4 w = *(const float4*)&sW2[(j + jj) * 4];
            o[0] = fmaf(sv, w.x, o[0]);
            o[1] = fmaf(sv, w.y, o[1]);
            o[2] = fmaf(sv, w.z, o[2]);
            o[3] = fmaf(sv, w.w, o[3]);
        }
    }
    *(float4*)&out[n * 4] = make_float4(o[0], o[1], o[2], o[3]);
}

// ---------------- fallback atomic edge MLP (reads bf16 tables) ----------------
template <int F, int STRIDE, bool DO_CNT>
__global__ __launch_bounds__(256) void edge_mlp_atomic_k(
    const ushort_t* __restrict__ feat,
    const int* __restrict__ row, const int* __restrict__ col,
    const float* __restrict__ eattr,
    const float* __restrict__ W1, const float* __restrict__ b1,
    const float* __restrict__ W2, const float* __restrict__ b2,
    float* __restrict__ agg, float* __restrict__ cnt)
{
    constexpr int IN = 2 * F + 4;
    __shared__ __align__(16) float sW1[IN * 64];
    __shared__ __align__(16) float sW2[64 * 32];
    __shared__ float sb1[64];
    __shared__ float sb2[32];
    for (int i = threadIdx.x; i < IN * 64; i += 256) sW1[i] = W1[i];
    for (int i = threadIdx.x; i < 64 * 32; i += 256) sW2[i] = W2[i];
    if (threadIdx.x < 64) sb1[threadIdx.x] = b1[threadIdx.x];
    if (threadIdx.x < 32) sb2[threadIdx.x] = b2[threadIdx.x];
    __syncthreads();
    int e = blockIdx.x * 256 + threadIdx.x;
    if (e >= EE) return;

    int r = row[e], c = col[e];
    float h[IN];
#pragma unroll
    for (int k = 0; k < F; k++) h[k] = bf2f(feat[(size_t)r * STRIDE + k]);
#pragma unroll
    for (int k = 0; k < F; k++) h[F + k] = bf2f(feat[(size_t)c * STRIDE + k]);
    float4 ev = *(const float4*)&eattr[(size_t)e * 4];
    h[2 * F] = ev.x; h[2 * F + 1] = ev.y; h[2 * F + 2] = ev.z; h[2 * F + 3] = ev.w;

    float out[32];
#pragma unroll
    for (int m = 0; m < 32; m++) out[m] = sb2[m];
#pragma unroll 1
    for (int j = 0; j < 64; j += 4) {
        float s[4] = {sb1[j], sb1[j + 1], sb1[j + 2], sb1[j + 3]};
#pragma unroll
        for (int k = 0; k < IN; k++) {
            float4 w = *(const float4*)&sW1[k * 64 + j];
            s[0] = fmaf(h[k], w.x, s[0]);
            s[1] = fmaf(h[k], w.y, s[1]);
            s[2] = fmaf(h[k], w.z, s[2]);
            s[3] = fmaf(h[k], w.w, s[3]);
        }
        s[0] = fmaxf(s[0], 0.f); s[1] = fmaxf(s[1], 0.f);
        s[2] = fmaxf(s[2], 0.f); s[3] = fmaxf(s[3], 0.f);
#pragma unroll
        for (int jj = 0; jj < 4; jj++) {
#pragma unroll
            for (int m = 0; m < 32; m += 4) {
                float4 w = *(const float4*)&sW2[(j + jj) * 32 + m];
                out[m]     = fmaf(s[jj], w.x, out[m]);
                out[m + 1] = fmaf(s[jj], w.y, out[m + 1]);
                out[m + 2] = fmaf(s[jj], w.z, out[m + 2]);
                out[m + 3] = fmaf(s[jj], w.w, out[m + 3]);
            }
        }
    }
    float* dst = &agg[(size_t)c * 32];
#pragma unroll
    for (int m = 0; m < 32; m++) atomicAdd(&dst[m], out[m]);
    if (DO_CNT) atomicAdd(&cnt[c], 1.0f);
}

extern "C" void kernel_launch(void* const* d_in, const int* in_sizes, int n_in,
                              void* d_out, int out_size, void* d_ws, size_t ws_size,
                              hipStream_t stream) {
    (void)in_sizes; (void)n_in; (void)out_size;
    const float* x      = (const float*)d_in[0];
    const float* u      = (const float*)d_in[1];
    const int*   ei     = (const int*)d_in[2];
    const float* eattr  = (const float*)d_in[3];
    const float* hn_h   = (const float*)d_in[4];
    const float* hn_c   = (const float*)d_in[5];
    const float* he_h   = (const float*)d_in[6];
    const float* he_c   = (const float*)d_in[7];
    const float* Wih_n  = (const float*)d_in[8];
    const float* Whh_n  = (const float*)d_in[9];
    const float* bih_n  = (const float*)d_in[10];
    const float* bhh_n  = (const float*)d_in[11];
    const float* Wih_e  = (const float*)d_in[12];
    const float* Whh_e  = (const float*)d_in[13];
    const float* bih_e  = (const float*)d_in[14];
    const float* bhh_e  = (const float*)d_in[15];
    const float* We1    = (const float*)d_in[16];
    const float* be1    = (const float*)d_in[17];
    const float* We2    = (const float*)d_in[18];
    const float* be2    = (const float*)d_in[19];
    const float* Wo1    = (const float*)d_in[20];
    const float* bo1    = (const float*)d_in[21];
    const float* Wo2    = (const float*)d_in[22];
    const float* bo2    = (const float*)d_in[23];
    const float* Wn1    = (const float*)d_in[24];
    const float* bn1    = (const float*)d_in[25];
    const float* Wn2    = (const float*)d_in[26];
    const float* bn2    = (const float*)d_in[27];

    const int* row = ei;
    const int* col = ei + EE;

    float* out = (float*)d_out;
    float* out_y   = out;                        // [N,4]
    float* node_h  = out + (size_t)NN * 4;       // [N,20]
    float* node_c  = out + (size_t)NN * 24;      // [N,20]
    float* edge_h  = out + (size_t)NN * 44;      // [N,8]
    float* edge_c  = out + (size_t)NN * 52;      // [N,8]

    int nb_n = (NN + 255) / 256;
    int nb_e = (EE + 255) / 256;
    int nb_n4 = (NN + 63) / 64;                  // 4 threads/node LSTM grid

    // ---- workspace layout ----
    ushort_t* xu16   = (ushort_t*)d_ws;
    ushort_t* full16 = xu16 + (size_t)NN * 40;
    float* agg  = (float*)(full16 + (size_t)NN * 32);
    float* cntf = agg + (size_t)NN * 32;
    float* agg2 = cntf + NN;
    int* count  = (int*)(agg2 + (size_t)NN * 32);
    int* cursor = count + NN;
    int* offset = cursor + NN;
    int* bsum   = offset + NN;
    int* bpre   = bsum + SBLK;
    size_t pw_off = ((size_t)((char*)(bpre + SBLK) - (char*)d_ws) + 15) & ~(size_t)15;
    ushort_t* pw = (ushort_t*)((char*)d_ws + pw_off);
    size_t edat_off = ((pw_off + (size_t)(PW1A + PW2A + PW1B + PW2B) * 2) + 15) & ~(size_t)15;
    uint4* edat = (uint4*)((char*)d_ws + edat_off);
    size_t needed = edat_off + (size_t)EE * 16;

    if (ws_size >= needed) {
        // zero agg | cntf | agg2 | count | cursor in one contiguous memset
        hipError_t _e = hipMemsetAsync(agg, 0, (size_t)NN * (32 + 1 + 32 + 1 + 1) * sizeof(float), stream);
        (void)_e;

        pack_w_k<<<1, 256, 0, stream>>>(We1, We2, Wo1, Wo2, pw);
        node_lstm_k<<<nb_n4, 256, 0, stream>>>(x, u, hn_h, hn_c, Wih_n, Whh_n, bih_n, bhh_n,
                                               xu16, node_h, node_c);
        csr_count_k<<<nb_e, 256, 0, stream>>>(col, count);
        scan1_k<<<SBLK, 256, 0, stream>>>(count, bsum);
        scan2_k<<<1, 256, 0, stream>>>(bsum, bpre);
        scan3_k<<<SBLK, 256, 0, stream>>>(count, bpre, offset, cntf);
        csr_fill4_k<<<nb_e, 256, 0, stream>>>(row, col, eattr, offset, cursor, edat);

        edge_mlp_fused_k<37, 40, 96><<<EE / 256, 256, 0, stream>>>(
            xu16, edat, offset, count, pw, be1, be2, agg);
        edge_lstm_k<<<nb_n, 256, 0, stream>>>(agg, cntf, he_h, he_c, Wih_e, Whh_e, bih_e, bhh_e,
                                              node_h, edge_h, edge_c, full16);
        edge_mlp_fused_k<28, 32, 64><<<EE / 256, 256, 0, stream>>>(
            full16, edat, offset, count, pw + PW1A + PW2A, bo1, bo2, agg2);
        node_out_k<<<nb_n, 256, 0, stream>>>(full16, agg2, cntf, Wn1, bn1, Wn2, bn2, out_y);
    } else {
        // fallback: atomic scatter path
        hipError_t _e = hipMemsetAsync(agg, 0, (size_t)NN * (32 + 1 + 32) * sizeof(float), stream);
        (void)_e;
        node_lstm_k<<<nb_n4, 256, 0, stream>>>(x, u, hn_h, hn_c, Wih_n, Whh_n, bih_n, bhh_n,
                                               xu16, node_h, node_c);
        edge_mlp_atomic_k<37, 40, true><<<nb_e, 256, 0, stream>>>(xu16, row, col, eattr,
                                                                  We1, be1, We2, be2, agg, cntf);
        edge_lstm_k<<<nb_n, 256, 0, stream>>>(agg, cntf, he_h, he_c, Wih_e, Whh_e, bih_e, bhh_e,
                                              node_h, edge_h, edge_c, full16);
        edge_mlp_atomic_k<28, 32, false><<<nb_e, 256, 0, stream>>>(full16, row, col, eattr,
                                                                   Wo1, bo1, Wo2, bo2, agg2, nullptr);
        node_out_k<<<nb_n, 256, 0, stream>>>(full16, agg2, cntf, Wn1, bn1, Wn2, bn2, out_y);
    }
}